// Round 1
// baseline (9441.008 us; speedup 1.0000x reference)
//
#include <hip/hip_runtime.h>
#include <hip/hip_bf16.h>
#include <math.h>

typedef __bf16 bf16;
typedef __bf16 bf16x8 __attribute__((ext_vector_type(8)));
typedef float  f32x4  __attribute__((ext_vector_type(4)));

#define B_  32
#define S_  512
#define H_  768
#define NH_ 12
#define DH_ 64
#define FF_ 3072
#define L_  12
#define M_  (B_*S_)   // 16384 token rows

// ---- async global->LDS, 16B per lane; lds base must be wave-uniform ----
__device__ __forceinline__ void gload16(const bf16* g, bf16* l) {
  __builtin_amdgcn_global_load_lds(
      (const __attribute__((address_space(1))) void*)g,
      (__attribute__((address_space(3))) void*)l, 16, 0, 0);
}

// ---------------- GEMM: C[M,N] = A[M,K]*(Bt[N,K])^T + bias ----------------
// epi: 0 -> bf16 out ; 1 -> f32 out ; 2 -> exact-GELU -> bf16 out
__global__ __launch_bounds__(256) void gemm_bf16(
    const bf16* __restrict__ A, const bf16* __restrict__ Bt,
    const float* __restrict__ bias, void* __restrict__ outp,
    int N, int K, int epi)
{
  __shared__ bf16 As[128*64];   // [row][k], k-contiguous
  __shared__ bf16 Bs[128*64];   // [col][k], k-contiguous
  const int tid  = threadIdx.x;
  const int lane = tid & 63, wid = tid >> 6;
  const int wr = wid >> 1, wc = wid & 1;
  const int m0 = blockIdx.y * 128, n0 = blockIdx.x * 128;
  const int lrow = lane & 15, kgrp = lane >> 4;
  const int srow = lane >> 3, scol = (lane & 7) * 8;
  f32x4 acc[4][4] = {};

  for (int k0 = 0; k0 < K; k0 += 64) {
    __syncthreads();                      // LDS reuse fence (prev compute done)
#pragma unroll
    for (int i = 0; i < 4; ++i) {
      int r0 = (wid * 4 + i) * 8;         // wave-uniform 8-row strip
      gload16(&A [(size_t)(m0 + r0 + srow) * K + k0 + scol], &As[r0 * 64]);
      gload16(&Bt[(size_t)(n0 + r0 + srow) * K + k0 + scol], &Bs[r0 * 64]);
    }
    __syncthreads();                      // drains vmcnt before barrier
#pragma unroll
    for (int kk = 0; kk < 64; kk += 32) {
      bf16x8 a[4], b[4];
#pragma unroll
      for (int m = 0; m < 4; ++m)
        a[m] = *(const bf16x8*)&As[(wr*64 + m*16 + lrow)*64 + kk + kgrp*8];
#pragma unroll
      for (int n = 0; n < 4; ++n)
        b[n] = *(const bf16x8*)&Bs[(wc*64 + n*16 + lrow)*64 + kk + kgrp*8];
#pragma unroll
      for (int m = 0; m < 4; ++m)
#pragma unroll
        for (int n = 0; n < 4; ++n)
          acc[m][n] = __builtin_amdgcn_mfma_f32_16x16x32_bf16(a[m], b[n], acc[m][n], 0, 0, 0);
    }
  }
  // epilogue: C/D layout col=lane&15, row=(lane>>4)*4+reg  [verified m89]
#pragma unroll
  for (int m = 0; m < 4; ++m) {
#pragma unroll
    for (int n = 0; n < 4; ++n) {
      int col = n0 + wc*64 + n*16 + lrow;
      float bv = bias[col];
#pragma unroll
      for (int r = 0; r < 4; ++r) {
        int row = m0 + wr*64 + m*16 + kgrp*4 + r;
        float x = acc[m][n][r] + bv;
        size_t idx = (size_t)row * N + col;
        if (epi == 1)      ((float*)outp)[idx] = x;
        else if (epi == 0) ((bf16*)outp)[idx]  = (bf16)x;
        else               ((bf16*)outp)[idx]  = (bf16)(0.5f * x * (1.0f + erff(x * 0.70710678118f)));
      }
    }
  }
}

// ---------------- weight transpose + fp32->bf16: W[K,N] -> Wt[N,K] ----------------
__global__ __launch_bounds__(256) void transpose_w(
    const float* __restrict__ W, bf16* __restrict__ Wt, int K, int N)
{
  __shared__ bf16 T[64][65];
  int k0 = blockIdx.x * 64, n0 = blockIdx.y * 64;
  int tx = threadIdx.x & 63, ty = threadIdx.x >> 6;   // ty 0..3
#pragma unroll
  for (int j = 0; j < 16; ++j) {
    int kk = j*4 + ty;
    T[kk][tx] = (bf16)W[(size_t)(k0+kk)*N + n0 + tx];
  }
  __syncthreads();
#pragma unroll
  for (int j = 0; j < 16; ++j) {
    int nn = j*4 + ty;
    Wt[(size_t)(n0+nn)*K + k0 + tx] = T[tx][nn];
  }
}

// ---------------- block reductions ----------------
__device__ __forceinline__ void block_sum2(float& a, float& b, float* red) {
  int lane = threadIdx.x & 63, wid = threadIdx.x >> 6;
  for (int o = 32; o > 0; o >>= 1) { a += __shfl_xor(a, o); b += __shfl_xor(b, o); }
  if (lane == 0) { red[wid*2] = a; red[wid*2+1] = b; }
  __syncthreads();
  a = red[0] + red[2] + red[4] + red[6];
  b = red[1] + red[3] + red[5] + red[7];
  __syncthreads();
}

// ---------------- embedding + LN ----------------
__global__ __launch_bounds__(256) void embed_ln(
    const int* __restrict__ ids, const float* __restrict__ we,
    const float* __restrict__ pe, const float* __restrict__ te,
    const float* __restrict__ gs, const float* __restrict__ gb,
    float* __restrict__ h32, bf16* __restrict__ hb)
{
  __shared__ float red[8];
  int row = blockIdx.x;
  int s = row & (S_-1);
  int id = ids[row];
  int t = threadIdx.x;
  float x[3], sum = 0.f, sq = 0.f;
#pragma unroll
  for (int j = 0; j < 3; ++j) {
    int c = t + j*256;
    float v = we[(size_t)id*H_ + c] + pe[(size_t)s*H_ + c] + te[c];
    x[j] = v; sum += v; sq += v*v;
  }
  block_sum2(sum, sq, red);
  float mean = sum * (1.f/H_);
  float var  = sq  * (1.f/H_) - mean*mean;
  float rstd = rsqrtf(fmaxf(var, 0.f) + 1e-12f);
#pragma unroll
  for (int j = 0; j < 3; ++j) {
    int c = t + j*256;
    float y = (x[j]-mean)*rstd*gs[c] + gb[c];
    h32[(size_t)row*H_ + c] = y;
    hb [(size_t)row*H_ + c] = (bf16)y;
  }
}

// ---------------- residual add + LN (fp32 path), writes f32 + bf16 ----------------
__global__ __launch_bounds__(256) void ln_res(
    const float* __restrict__ t32, const float* __restrict__ res,
    const float* __restrict__ gs, const float* __restrict__ gb,
    float* __restrict__ o32, bf16* __restrict__ ob)
{
  __shared__ float red[8];
  int row = blockIdx.x, t = threadIdx.x;
  float x[3], sum = 0.f, sq = 0.f;
#pragma unroll
  for (int j = 0; j < 3; ++j) {
    int c = t + j*256;
    float v = t32[(size_t)row*H_ + c] + res[(size_t)row*H_ + c];
    x[j] = v; sum += v; sq += v*v;
  }
  block_sum2(sum, sq, red);
  float mean = sum * (1.f/H_);
  float var  = sq  * (1.f/H_) - mean*mean;
  float rstd = rsqrtf(fmaxf(var, 0.f) + 1e-12f);
#pragma unroll
  for (int j = 0; j < 3; ++j) {
    int c = t + j*256;
    float y = (x[j]-mean)*rstd*gs[c] + gb[c];
    o32[(size_t)row*H_ + c] = y;
    ob [(size_t)row*H_ + c] = (bf16)y;
  }
}

// ---------------- fused attention: one block per (b, head, query-half) ----------------
// softmax(S)*mask/renorm  ==  exp(S-max)*mask / sum(exp(S-max)*mask)   (denominator cancels)
__global__ __launch_bounds__(256) void attn_kernel(
    const bf16* __restrict__ Q, const bf16* __restrict__ Kg,
    const bf16* __restrict__ Vg, const float* __restrict__ mask,
    bf16* __restrict__ ctx)
{
  __shared__ bf16 Kl[S_*DH_];      // [key][d]      64 KB
  __shared__ bf16 Vt[DH_*S_];      // [d][key]      64 KB
  __shared__ float mk[S_];         //                2 KB
  __shared__ bf16 Pl[4][16*64];    // per-wave P    8 KB   (total ~141 KB)
  int bid = blockIdx.x;
  int half = bid & 1, bh = bid >> 1;
  int h = bh % NH_, b = bh / NH_;
  int tid = threadIdx.x, lane = tid & 63, wid = tid >> 6;
  int lrow = lane & 15, kgrp = lane >> 4;
  const bf16* Kb = Kg + (size_t)(b*S_)*H_ + h*DH_;
  const bf16* Vb = Vg + (size_t)(b*S_)*H_ + h*DH_;

  for (int it = 0; it < 16; ++it) {               // stage K row-major
    int slot = it*256 + tid;
    int s = slot >> 3, c8 = (slot & 7)*8;
    *(bf16x8*)&Kl[s*DH_ + c8] = *(const bf16x8*)&Kb[(size_t)s*H_ + c8];
  }
  for (int it = 0; it < 16; ++it) {               // stage V transposed
    int slot = it*256 + tid;
    int s = slot >> 3, c8 = (slot & 7)*8;
    bf16x8 v = *(const bf16x8*)&Vb[(size_t)s*H_ + c8];
#pragma unroll
    for (int i = 0; i < 8; ++i) Vt[(c8+i)*S_ + s] = v[i];
  }
  mk[tid]       = mask[b*S_ + tid];
  mk[tid + 256] = mask[b*S_ + 256 + tid];
  __syncthreads();

  for (int pass = 0; pass < 4; ++pass) {
    int q0 = half*256 + pass*64 + wid*16;
    bf16x8 qa[2];
#pragma unroll
    for (int kc = 0; kc < 2; ++kc)
      qa[kc] = *(const bf16x8*)&Q[(size_t)(b*S_ + q0 + lrow)*H_ + h*DH_ + kc*32 + kgrp*8];
    f32x4 O[4] = {};
    float mrun[4], lrun[4];
#pragma unroll
    for (int r = 0; r < 4; ++r) { mrun[r] = -1e30f; lrun[r] = 0.f; }

    for (int c0 = 0; c0 < S_; c0 += 64) {
      f32x4 Sf[4] = {};
#pragma unroll
      for (int kc = 0; kc < 2; ++kc)
#pragma unroll
        for (int sn = 0; sn < 4; ++sn) {
          bf16x8 kbv = *(const bf16x8*)&Kl[(c0 + sn*16 + lrow)*DH_ + kc*32 + kgrp*8];
          Sf[sn] = __builtin_amdgcn_mfma_f32_16x16x32_bf16(qa[kc], kbv, Sf[sn], 0, 0, 0);
        }
      float cmax[4];
#pragma unroll
      for (int r = 0; r < 4; ++r) cmax[r] = -1e30f;
#pragma unroll
      for (int sn = 0; sn < 4; ++sn)
#pragma unroll
        for (int r = 0; r < 4; ++r) {
          Sf[sn][r] *= 0.125f;                    // 1/sqrt(64)
          cmax[r] = fmaxf(cmax[r], Sf[sn][r]);
        }
      for (int o = 1; o < 16; o <<= 1)
#pragma unroll
        for (int r = 0; r < 4; ++r) cmax[r] = fmaxf(cmax[r], __shfl_xor(cmax[r], o));
      float newm[4], fr[4], lsum[4];
#pragma unroll
      for (int r = 0; r < 4; ++r) {
        newm[r] = fmaxf(mrun[r], cmax[r]);
        fr[r]   = __expf(mrun[r] - newm[r]);
        lsum[r] = 0.f;
      }
#pragma unroll
      for (int sn = 0; sn < 4; ++sn) {
        float mkv = mk[c0 + sn*16 + lrow];
#pragma unroll
        for (int r = 0; r < 4; ++r) {
          float e = __expf(Sf[sn][r] - newm[r]) * mkv;
          bf16 eb = (bf16)e;
          lsum[r] += (float)eb;                   // denom matches rounded P
          Pl[wid][(kgrp*4 + r)*64 + sn*16 + lrow] = eb;
        }
      }
      for (int o = 1; o < 16; o <<= 1)
#pragma unroll
        for (int r = 0; r < 4; ++r) lsum[r] += __shfl_xor(lsum[r], o);
#pragma unroll
      for (int r = 0; r < 4; ++r) { lrun[r] = lrun[r]*fr[r] + lsum[r]; mrun[r] = newm[r]; }
#pragma unroll
      for (int on = 0; on < 4; ++on)
#pragma unroll
        for (int r = 0; r < 4; ++r) O[on][r] *= fr[r];
      asm volatile("s_waitcnt lgkmcnt(0)" ::: "memory");   // intra-wave P handoff
      __builtin_amdgcn_sched_barrier(0);
#pragma unroll
      for (int kc = 0; kc < 2; ++kc) {
        bf16x8 pa = *(const bf16x8*)&Pl[wid][lrow*64 + kc*32 + kgrp*8];
#pragma unroll
        for (int on = 0; on < 4; ++on) {
          bf16x8 vv = *(const bf16x8*)&Vt[(on*16 + lrow)*S_ + c0 + kc*32 + kgrp*8];
          O[on] = __builtin_amdgcn_mfma_f32_16x16x32_bf16(pa, vv, O[on], 0, 0, 0);
        }
      }
    }
#pragma unroll
    for (int on = 0; on < 4; ++on)
#pragma unroll
      for (int r = 0; r < 4; ++r) {
        float val = O[on][r] / fmaxf(lrun[r], 1e-9f);
        int q = q0 + kgrp*4 + r;
        ctx[(size_t)(b*S_ + q)*H_ + h*DH_ + on*16 + lrow] = (bf16)val;
      }
  }
}

// ---------------- masked mean pool + L2 normalize ----------------
__global__ __launch_bounds__(256) void pool_norm(
    const float* __restrict__ h32, const float* __restrict__ mask,
    float* __restrict__ out)
{
  __shared__ float red[8];
  int b = blockIdx.x, t = threadIdx.x;
  float a0 = 0.f, a1 = 0.f, a2 = 0.f;
  for (int s = 0; s < S_; ++s) {
    float m = mask[b*S_ + s];
    const float* hp = &h32[((size_t)b*S_ + s)*H_];
    a0 += hp[t]*m; a1 += hp[t+256]*m; a2 += hp[t+512]*m;
  }
  float msum = mask[b*S_ + t] + mask[b*S_ + 256 + t];
  float dummy = 0.f;
  block_sum2(msum, dummy, red);
  float inv = 1.f / fmaxf(msum, 1e-6f);
  float s0 = a0*inv, s1 = a1*inv, s2 = a2*inv;
  float nrm = s0*s0 + s1*s1 + s2*s2;
  dummy = 0.f;
  block_sum2(nrm, dummy, red);
  float rn = 1.f / fmaxf(sqrtf(nrm), 1e-12f);
  out[b*H_ + t]       = s0*rn;
  out[b*H_ + t + 256] = s1*rn;
  out[b*H_ + t + 512] = s2*rn;
}

// ---------------- host driver ----------------
extern "C" void kernel_launch(void* const* d_in, const int* in_sizes, int n_in,
                              void* d_out, int out_size, void* d_ws, size_t ws_size,
                              hipStream_t stream)
{
  const int*   ids  = (const int*)  d_in[0];
  const float* mask = (const float*)d_in[1];
  const float* we   = (const float*)d_in[2];
  const float* pe   = (const float*)d_in[3];
  const float* te   = (const float*)d_in[4];
  const float* les  = (const float*)d_in[5];
  const float* leb  = (const float*)d_in[6];
  const float* Wq   = (const float*)d_in[7];
  const float* bq   = (const float*)d_in[8];
  const float* Wk   = (const float*)d_in[9];
  const float* bk   = (const float*)d_in[10];
  const float* Wv   = (const float*)d_in[11];
  const float* bv   = (const float*)d_in[12];
  const float* Wo   = (const float*)d_in[13];
  const float* bo   = (const float*)d_in[14];
  const float* l1s  = (const float*)d_in[15];
  const float* l1b  = (const float*)d_in[16];
  const float* Wi   = (const float*)d_in[17];
  const float* bi   = (const float*)d_in[18];
  const float* Wf   = (const float*)d_in[19];
  const float* bfp  = (const float*)d_in[20];
  const float* l2s  = (const float*)d_in[21];
  const float* l2b  = (const float*)d_in[22];

  // ws carve-out (~374 MB total)
  char* p = (char*)d_ws;
  auto alloc = [&](size_t bytes) { char* q = p; p += (bytes + 255) & ~(size_t)255; return q; };
  bf16*  wqt = (bf16*) alloc((size_t)H_*H_*2);
  bf16*  wkt = (bf16*) alloc((size_t)H_*H_*2);
  bf16*  wvt = (bf16*) alloc((size_t)H_*H_*2);
  bf16*  wot = (bf16*) alloc((size_t)H_*H_*2);
  bf16*  wit = (bf16*) alloc((size_t)H_*FF_*2);
  bf16*  wft = (bf16*) alloc((size_t)H_*FF_*2);
  bf16*  hb  = (bf16*) alloc((size_t)M_*H_*2);    // bf16 hidden (GEMM A operand)
  float* h32 = (float*)alloc((size_t)M_*H_*4);    // fp32 residual stream
  float* a32 = (float*)alloc((size_t)M_*H_*4);    // fp32 post-attn hidden
  float* tmp = (float*)alloc((size_t)M_*H_*4);    // fp32 pre-LN GEMM out
  bf16*  qb  = (bf16*) alloc((size_t)M_*H_*2);
  bf16*  kb2 = (bf16*) alloc((size_t)M_*H_*2);
  bf16*  vb2 = (bf16*) alloc((size_t)M_*H_*2);
  bf16*  cxb = (bf16*) alloc((size_t)M_*H_*2);
  bf16*  inb = (bf16*) alloc((size_t)M_*FF_*2);

  embed_ln<<<M_, 256, 0, stream>>>(ids, we, pe, te, les, leb, h32, hb);

  for (int l = 0; l < L_; ++l) {
    size_t wsq = (size_t)l*H_*H_;
    transpose_w<<<dim3(H_/64,  H_/64 ), 256, 0, stream>>>(Wq + wsq, wqt, H_, H_);
    transpose_w<<<dim3(H_/64,  H_/64 ), 256, 0, stream>>>(Wk + wsq, wkt, H_, H_);
    transpose_w<<<dim3(H_/64,  H_/64 ), 256, 0, stream>>>(Wv + wsq, wvt, H_, H_);
    transpose_w<<<dim3(H_/64,  H_/64 ), 256, 0, stream>>>(Wo + wsq, wot, H_, H_);
    transpose_w<<<dim3(H_/64,  FF_/64), 256, 0, stream>>>(Wi + (size_t)l*H_*FF_, wit, H_, FF_);
    transpose_w<<<dim3(FF_/64, H_/64 ), 256, 0, stream>>>(Wf + (size_t)l*FF_*H_, wft, FF_, H_);

    gemm_bf16<<<dim3(H_/128,  M_/128), 256, 0, stream>>>(hb,  wqt, bq  + l*H_,  qb,  H_,  H_,  0);
    gemm_bf16<<<dim3(H_/128,  M_/128), 256, 0, stream>>>(hb,  wkt, bk  + l*H_,  kb2, H_,  H_,  0);
    gemm_bf16<<<dim3(H_/128,  M_/128), 256, 0, stream>>>(hb,  wvt, bv  + l*H_,  vb2, H_,  H_,  0);
    attn_kernel<<<B_*NH_*2, 256, 0, stream>>>(qb, kb2, vb2, mask, cxb);
    gemm_bf16<<<dim3(H_/128,  M_/128), 256, 0, stream>>>(cxb, wot, bo  + l*H_,  tmp, H_,  H_,  1);
    ln_res<<<M_, 256, 0, stream>>>(tmp, h32, l1s + l*H_, l1b + l*H_, a32, hb);
    gemm_bf16<<<dim3(FF_/128, M_/128), 256, 0, stream>>>(hb,  wit, bi  + l*FF_, inb, FF_, H_,  2);
    gemm_bf16<<<dim3(H_/128,  M_/128), 256, 0, stream>>>(inb, wft, bfp + l*H_,  tmp, H_,  FF_, 1);
    ln_res<<<M_, 256, 0, stream>>>(tmp, a32, l2s + l*H_, l2b + l*H_, h32, hb);
  }

  pool_norm<<<B_, 256, 0, stream>>>(h32, mask, (float*)d_out);
}

// Round 2
// 7938.010 us; speedup vs baseline: 1.1893x; 1.1893x over previous
//
#include <hip/hip_runtime.h>
#include <hip/hip_bf16.h>
#include <math.h>

typedef __bf16 bf16;
typedef __bf16 bf16x8 __attribute__((ext_vector_type(8)));
typedef float  f32x4  __attribute__((ext_vector_type(4)));

#define B_  32
#define S_  512
#define H_  768
#define NH_ 12
#define DH_ 64
#define FF_ 3072
#define L_  12
#define M_  (B_*S_)
#define QKV_ 2304   // packed q|k|v row stride

// ---- async global->LDS, 16B per lane; lds base must be wave-uniform ----
__device__ __forceinline__ void gload16(const bf16* g, bf16* l) {
  __builtin_amdgcn_global_load_lds(
      (const __attribute__((address_space(1))) void*)g,
      (__attribute__((address_space(3))) void*)l, 16, 0, 0);
}

// =================== 256x256 8-phase GEMM ===================
// C[M,N] = A[M,K] * Bt[N,K]^T + bias.  epi: 0 bf16, 1 f32, 2 gelu->bf16
// LDS swizzle: 16B-slot s stored at s ^ (row&7); source pre-swizzled, read swizzled.
__global__ __launch_bounds__(512, 2) void gemm256(
    const bf16* __restrict__ A, const bf16* __restrict__ Bt,
    const float* __restrict__ bias, void* __restrict__ outp,
    int N, int K, int tiles_n, int epi)
{
  __shared__ bf16 sm[2][2][256*64];   // [buf][A|B][row*64 + col] : 128 KB
  const int tid  = threadIdx.x;
  const int lane = tid & 63, wid = tid >> 6;
  const int wr = wid >> 2, wc = wid & 3;          // 2 x 4 wave grid
  const int lrow = lane & 15, kgrp = lane >> 4;

  // bijective XCD swizzle (m204)
  const int nwg = gridDim.x, orig = blockIdx.x;
  const int qc = nwg >> 3, rc = nwg & 7;
  const int xcd = orig & 7, lin = orig >> 3;
  const int wg = (xcd < rc ? xcd*(qc+1) : rc*(qc+1) + (xcd-rc)*qc) + lin;
  const int tm = wg / tiles_n, tn = wg % tiles_n;
  const size_t m0 = (size_t)tm * 256, n0 = (size_t)tn * 256;
  const int KT = K >> 6;

  const bf16* Ab = A  + m0 * K;
  const bf16* Bb = Bt + n0 * K;

  // stage one 128-row half (16 KB): 2 gload16 per thread; source pre-swizzled
  auto stage_half = [&](int buf, int ab, int row0, const bf16* gbase, int kt) {
#pragma unroll
    for (int j = 0; j < 2; ++j) {
      int lin2  = j*512 + tid;
      int prow  = lin2 >> 3;             // 0..127
      int pslot = lin2 & 7;              // physical 16B slot
      int lslot = pslot ^ (prow & 7);    // logical slot (involution)
      const bf16* src = gbase + (size_t)(row0 + prow) * K + (size_t)kt*64 + lslot*8;
      bf16* dst = &sm[buf][ab][row0*64 + (j*512 + (wid<<6))*8];  // wave-uniform base
      gload16(src, dst);
    }
  };

  f32x4 acc[2][2][4][2] = {};   // [mh][nh][m][n]

  // ---- prologue: tile0 (A0,B0,A1,B1)->buf0, tile1 (A0,B0)->buf1 : 12 loads
  stage_half(0, 0, 0,   Ab, 0);
  stage_half(0, 1, 0,   Bb, 0);
  stage_half(0, 0, 128, Ab, 0);
  stage_half(0, 1, 128, Bb, 0);
  stage_half(1, 0, 0,   Ab, 1);
  stage_half(1, 1, 0,   Bb, 1);
  asm volatile("s_waitcnt vmcnt(8)" ::: "memory");   // retire tile0 A0,B0
  __builtin_amdgcn_s_barrier();

#define PHASE(MH, NH, ISSUE, WAITV)                                           \
  {                                                                           \
    bf16x8 af[4][2], bfv[2][2];                                               \
    _Pragma("unroll") for (int m = 0; m < 4; ++m)                             \
      _Pragma("unroll") for (int kk = 0; kk < 2; ++kk) {                      \
        int row  = MH*128 + wr*64 + m*16 + lrow;                              \
        int slot = (kk*4 + kgrp) ^ (lrow & 7);                                \
        af[m][kk] = *(const bf16x8*)&As[row*64 + slot*8];                     \
      }                                                                       \
    _Pragma("unroll") for (int n = 0; n < 2; ++n)                             \
      _Pragma("unroll") for (int kk = 0; kk < 2; ++kk) {                      \
        int row  = NH*128 + wc*32 + n*16 + lrow;                              \
        int slot = (kk*4 + kgrp) ^ (lrow & 7);                                \
        bfv[n][kk] = *(const bf16x8*)&Bs[row*64 + slot*8];                    \
      }                                                                       \
    ISSUE;                                                                    \
    __builtin_amdgcn_s_barrier();                                             \
    asm volatile("s_waitcnt lgkmcnt(0)" ::: "memory");                        \
    __builtin_amdgcn_sched_barrier(0);                                        \
    __builtin_amdgcn_s_setprio(1);                                            \
    _Pragma("unroll") for (int kk = 0; kk < 2; ++kk)                          \
      _Pragma("unroll") for (int m = 0; m < 4; ++m)                           \
        _Pragma("unroll") for (int n = 0; n < 2; ++n)                         \
          acc[MH][NH][m][n] = __builtin_amdgcn_mfma_f32_16x16x32_bf16(        \
              af[m][kk], bfv[n][kk], acc[MH][NH][m][n], 0, 0, 0);             \
    __builtin_amdgcn_s_setprio(0);                                            \
    WAITV;                                                                    \
    __builtin_amdgcn_s_barrier();                                             \
  }

  for (int t = 0; t < KT; ++t) {
    const int cur = t & 1;
    bf16* As = sm[cur][0];
    bf16* Bs = sm[cur][1];
    const int t1 = (t+1 < KT) ? t+1 : KT-1;   // clamped (keeps vmcnt ledger uniform)
    const int t2 = (t+2 < KT) ? t+2 : KT-1;
    const int b1 = (t+1) & 1, b2 = t & 1;

    // p0 (mh0,nh0): issue A1(t+1); retire up through B1(t)
    PHASE(0, 0,
          stage_half(b1, 0, 128, Ab, t1),
          asm volatile("s_waitcnt vmcnt(6)" ::: "memory"));
    // p1 (mh0,nh1): issue B1(t+1)
    PHASE(0, 1,
          stage_half(b1, 1, 128, Bb, t1), );
    // p2 (mh1,nh0): issue A0(t+2) into cur (A-half0 dead after p1)
    PHASE(1, 0,
          stage_half(b2, 0, 0, Ab, t2), );
    // p3 (mh1,nh1): issue B0(t+2) into cur; retire A0/B0(t+1)
    PHASE(1, 1,
          stage_half(b2, 1, 0, Bb, t2),
          asm volatile("s_waitcnt vmcnt(8)" ::: "memory"));
  }
#undef PHASE

  // ---- epilogue: row = ...+kgrp*4+r (A side), col = ...+lrow (B side)
#pragma unroll
  for (int mh = 0; mh < 2; ++mh)
#pragma unroll
    for (int nh = 0; nh < 2; ++nh)
#pragma unroll
      for (int n = 0; n < 2; ++n) {
        int col = (int)n0 + nh*128 + wc*32 + n*16 + lrow;
        float bv = bias[col];
#pragma unroll
        for (int m = 0; m < 4; ++m)
#pragma unroll
          for (int r = 0; r < 4; ++r) {
            int row = (int)m0 + mh*128 + wr*64 + m*16 + kgrp*4 + r;
            float x = acc[mh][nh][m][n][r] + bv;
            size_t idx = (size_t)row * N + col;
            if (epi == 1)      ((float*)outp)[idx] = x;
            else if (epi == 0) ((bf16*)outp)[idx]  = (bf16)x;
            else               ((bf16*)outp)[idx]  = (bf16)(0.5f * x * (1.0f + erff(x * 0.70710678118f)));
          }
      }
}

// ---------------- weight transpose + fp32->bf16: W[K,N] -> Wt[N,K] ----------------
__global__ __launch_bounds__(256) void transpose_w(
    const float* __restrict__ W, bf16* __restrict__ Wt, int K, int N)
{
  __shared__ bf16 T[64][65];
  int k0 = blockIdx.x * 64, n0 = blockIdx.y * 64;
  int tx = threadIdx.x & 63, ty = threadIdx.x >> 6;
#pragma unroll
  for (int j = 0; j < 16; ++j) {
    int kk = j*4 + ty;
    T[kk][tx] = (bf16)W[(size_t)(k0+kk)*N + n0 + tx];
  }
  __syncthreads();
#pragma unroll
  for (int j = 0; j < 16; ++j) {
    int nn = j*4 + ty;
    Wt[(size_t)(n0+nn)*K + k0 + tx] = T[tx][nn];
  }
}

__global__ __launch_bounds__(256) void pack_qkv_bias(
    const float* __restrict__ bq, const float* __restrict__ bk,
    const float* __restrict__ bv, float* __restrict__ out)
{
  int i = blockIdx.x*256 + threadIdx.x;
  out[i] = (i < 768) ? bq[i] : (i < 1536 ? bk[i-768] : bv[i-1536]);
}

// ---------------- block reductions ----------------
__device__ __forceinline__ void block_sum2(float& a, float& b, float* red) {
  int lane = threadIdx.x & 63, wid = threadIdx.x >> 6;
  for (int o = 32; o > 0; o >>= 1) { a += __shfl_xor(a, o); b += __shfl_xor(b, o); }
  if (lane == 0) { red[wid*2] = a; red[wid*2+1] = b; }
  __syncthreads();
  a = red[0] + red[2] + red[4] + red[6];
  b = red[1] + red[3] + red[5] + red[7];
  __syncthreads();
}

// ---------------- embedding + LN ----------------
__global__ __launch_bounds__(256) void embed_ln(
    const int* __restrict__ ids, const float* __restrict__ we,
    const float* __restrict__ pe, const float* __restrict__ te,
    const float* __restrict__ gs, const float* __restrict__ gb,
    float* __restrict__ h32, bf16* __restrict__ hb)
{
  __shared__ float red[8];
  int row = blockIdx.x;
  int s = row & (S_-1);
  int id = ids[row];
  int t = threadIdx.x;
  float x[3], sum = 0.f, sq = 0.f;
#pragma unroll
  for (int j = 0; j < 3; ++j) {
    int c = t + j*256;
    float v = we[(size_t)id*H_ + c] + pe[(size_t)s*H_ + c] + te[c];
    x[j] = v; sum += v; sq += v*v;
  }
  block_sum2(sum, sq, red);
  float mean = sum * (1.f/H_);
  float var  = sq  * (1.f/H_) - mean*mean;
  float rstd = rsqrtf(fmaxf(var, 0.f) + 1e-12f);
#pragma unroll
  for (int j = 0; j < 3; ++j) {
    int c = t + j*256;
    float y = (x[j]-mean)*rstd*gs[c] + gb[c];
    h32[(size_t)row*H_ + c] = y;
    hb [(size_t)row*H_ + c] = (bf16)y;
  }
}

// ---------------- residual add + LN ----------------
__global__ __launch_bounds__(256) void ln_res(
    const float* __restrict__ t32, const float* __restrict__ res,
    const float* __restrict__ gs, const float* __restrict__ gb,
    float* __restrict__ o32, bf16* __restrict__ ob)
{
  __shared__ float red[8];
  int row = blockIdx.x, t = threadIdx.x;
  float x[3], sum = 0.f, sq = 0.f;
#pragma unroll
  for (int j = 0; j < 3; ++j) {
    int c = t + j*256;
    float v = t32[(size_t)row*H_ + c] + res[(size_t)row*H_ + c];
    x[j] = v; sum += v; sq += v*v;
  }
  block_sum2(sum, sq, red);
  float mean = sum * (1.f/H_);
  float var  = sq  * (1.f/H_) - mean*mean;
  float rstd = rsqrtf(fmaxf(var, 0.f) + 1e-12f);
#pragma unroll
  for (int j = 0; j < 3; ++j) {
    int c = t + j*256;
    float y = (x[j]-mean)*rstd*gs[c] + gb[c];
    o32[(size_t)row*H_ + c] = y;
    ob [(size_t)row*H_ + c] = (bf16)y;
  }
}

// ---------------- fused attention (reads packed qkv, stride 2304) ----------------
__global__ __launch_bounds__(256) void attn_kernel(
    const bf16* __restrict__ qkv, const float* __restrict__ mask,
    bf16* __restrict__ ctx)
{
  __shared__ bf16 Kl[S_*DH_];
  __shared__ bf16 Vt[DH_*S_];
  __shared__ float mk[S_];
  __shared__ bf16 Pl[4][16*64];
  int bid = blockIdx.x;
  int half = bid & 1, bh = bid >> 1;
  int h = bh % NH_, b = bh / NH_;
  int tid = threadIdx.x, lane = tid & 63, wid = tid >> 6;
  int lrow = lane & 15, kgrp = lane >> 4;
  const bf16* Kb = qkv + (size_t)(b*S_)*QKV_ + H_   + h*DH_;
  const bf16* Vb = qkv + (size_t)(b*S_)*QKV_ + 2*H_ + h*DH_;
  const bf16* Qb = qkv + (size_t)(b*S_)*QKV_        + h*DH_;

  for (int it = 0; it < 16; ++it) {
    int slot = it*256 + tid;
    int s = slot >> 3, c8 = (slot & 7)*8;
    *(bf16x8*)&Kl[s*DH_ + c8] = *(const bf16x8*)&Kb[(size_t)s*QKV_ + c8];
  }
  for (int it = 0; it < 16; ++it) {
    int slot = it*256 + tid;
    int s = slot >> 3, c8 = (slot & 7)*8;
    bf16x8 v = *(const bf16x8*)&Vb[(size_t)s*QKV_ + c8];
#pragma unroll
    for (int i = 0; i < 8; ++i) Vt[(c8+i)*S_ + s] = v[i];
  }
  mk[tid]       = mask[b*S_ + tid];
  mk[tid + 256] = mask[b*S_ + 256 + tid];
  __syncthreads();

  for (int pass = 0; pass < 4; ++pass) {
    int q0 = half*256 + pass*64 + wid*16;
    bf16x8 qa[2];
#pragma unroll
    for (int kc = 0; kc < 2; ++kc)
      qa[kc] = *(const bf16x8*)&Qb[(size_t)(q0 + lrow)*QKV_ + kc*32 + kgrp*8];
    f32x4 O[4] = {};
    float mrun[4], lrun[4];
#pragma unroll
    for (int r = 0; r < 4; ++r) { mrun[r] = -1e30f; lrun[r] = 0.f; }

    for (int c0 = 0; c0 < S_; c0 += 64) {
      f32x4 Sf[4] = {};
#pragma unroll
      for (int kc = 0; kc < 2; ++kc)
#pragma unroll
        for (int sn = 0; sn < 4; ++sn) {
          bf16x8 kbv = *(const bf16x8*)&Kl[(c0 + sn*16 + lrow)*DH_ + kc*32 + kgrp*8];
          Sf[sn] = __builtin_amdgcn_mfma_f32_16x16x32_bf16(qa[kc], kbv, Sf[sn], 0, 0, 0);
        }
      float cmax[4];
#pragma unroll
      for (int r = 0; r < 4; ++r) cmax[r] = -1e30f;
#pragma unroll
      for (int sn = 0; sn < 4; ++sn)
#pragma unroll
        for (int r = 0; r < 4; ++r) {
          Sf[sn][r] *= 0.125f;
          cmax[r] = fmaxf(cmax[r], Sf[sn][r]);
        }
      for (int o = 1; o < 16; o <<= 1)
#pragma unroll
        for (int r = 0; r < 4; ++r) cmax[r] = fmaxf(cmax[r], __shfl_xor(cmax[r], o));
      float newm[4], fr[4], lsum[4];
#pragma unroll
      for (int r = 0; r < 4; ++r) {
        newm[r] = fmaxf(mrun[r], cmax[r]);
        fr[r]   = __expf(mrun[r] - newm[r]);
        lsum[r] = 0.f;
      }
#pragma unroll
      for (int sn = 0; sn < 4; ++sn) {
        float mkv = mk[c0 + sn*16 + lrow];
#pragma unroll
        for (int r = 0; r < 4; ++r) {
          float e = __expf(Sf[sn][r] - newm[r]) * mkv;
          bf16 eb = (bf16)e;
          lsum[r] += (float)eb;
          Pl[wid][(kgrp*4 + r)*64 + sn*16 + lrow] = eb;
        }
      }
      for (int o = 1; o < 16; o <<= 1)
#pragma unroll
        for (int r = 0; r < 4; ++r) lsum[r] += __shfl_xor(lsum[r], o);
#pragma unroll
      for (int r = 0; r < 4; ++r) { lrun[r] = lrun[r]*fr[r] + lsum[r]; mrun[r] = newm[r]; }
#pragma unroll
      for (int on = 0; on < 4; ++on)
#pragma unroll
        for (int r = 0; r < 4; ++r) O[on][r] *= fr[r];
      asm volatile("s_waitcnt lgkmcnt(0)" ::: "memory");
      __builtin_amdgcn_sched_barrier(0);
#pragma unroll
      for (int kc = 0; kc < 2; ++kc) {
        bf16x8 pa = *(const bf16x8*)&Pl[wid][lrow*64 + kc*32 + kgrp*8];
#pragma unroll
        for (int on = 0; on < 4; ++on) {
          bf16x8 vv = *(const bf16x8*)&Vt[(on*16 + lrow)*S_ + c0 + kc*32 + kgrp*8];
          O[on] = __builtin_amdgcn_mfma_f32_16x16x32_bf16(pa, vv, O[on], 0, 0, 0);
        }
      }
    }
#pragma unroll
    for (int on = 0; on < 4; ++on)
#pragma unroll
      for (int r = 0; r < 4; ++r) {
        float val = O[on][r] / fmaxf(lrun[r], 1e-9f);
        int q = q0 + kgrp*4 + r;
        ctx[(size_t)(b*S_ + q)*H_ + h*DH_ + on*16 + lrow] = (bf16)val;
      }
  }
}

// ---------------- masked mean pool + L2 normalize ----------------
__global__ __launch_bounds__(256) void pool_norm(
    const float* __restrict__ h32, const float* __restrict__ mask,
    float* __restrict__ out)
{
  __shared__ float red[8];
  int b = blockIdx.x, t = threadIdx.x;
  float a0 = 0.f, a1 = 0.f, a2 = 0.f;
  for (int s = 0; s < S_; ++s) {
    float m = mask[b*S_ + s];
    const float* hp = &h32[((size_t)b*S_ + s)*H_];
    a0 += hp[t]*m; a1 += hp[t+256]*m; a2 += hp[t+512]*m;
  }
  float msum = mask[b*S_ + t] + mask[b*S_ + 256 + t];
  float dummy = 0.f;
  block_sum2(msum, dummy, red);
  float inv = 1.f / fmaxf(msum, 1e-6f);
  float s0 = a0*inv, s1 = a1*inv, s2 = a2*inv;
  float nrm = s0*s0 + s1*s1 + s2*s2;
  dummy = 0.f;
  block_sum2(nrm, dummy, red);
  float rn = 1.f / fmaxf(sqrtf(nrm), 1e-12f);
  out[b*H_ + t]       = s0*rn;
  out[b*H_ + t + 256] = s1*rn;
  out[b*H_ + t + 512] = s2*rn;
}

// ---------------- host driver ----------------
extern "C" void kernel_launch(void* const* d_in, const int* in_sizes, int n_in,
                              void* d_out, int out_size, void* d_ws, size_t ws_size,
                              hipStream_t stream)
{
  const int*   ids  = (const int*)  d_in[0];
  const float* mask = (const float*)d_in[1];
  const float* we   = (const float*)d_in[2];
  const float* pe   = (const float*)d_in[3];
  const float* te   = (const float*)d_in[4];
  const float* les  = (const float*)d_in[5];
  const float* leb  = (const float*)d_in[6];
  const float* Wq   = (const float*)d_in[7];
  const float* bq   = (const float*)d_in[8];
  const float* Wk   = (const float*)d_in[9];
  const float* bk   = (const float*)d_in[10];
  const float* Wv   = (const float*)d_in[11];
  const float* bv   = (const float*)d_in[12];
  const float* Wo   = (const float*)d_in[13];
  const float* bo   = (const float*)d_in[14];
  const float* l1s  = (const float*)d_in[15];
  const float* l1b  = (const float*)d_in[16];
  const float* Wi   = (const float*)d_in[17];
  const float* bi   = (const float*)d_in[18];
  const float* Wf   = (const float*)d_in[19];
  const float* bfp  = (const float*)d_in[20];
  const float* l2s  = (const float*)d_in[21];
  const float* l2b  = (const float*)d_in[22];

  char* p = (char*)d_ws;
  auto alloc = [&](size_t bytes) { char* q = p; p += (bytes + 255) & ~(size_t)255; return q; };
  bf16*  wqkv = (bf16*) alloc((size_t)QKV_*H_*2);   // packed [2304][768]
  bf16*  wot  = (bf16*) alloc((size_t)H_*H_*2);
  bf16*  wit  = (bf16*) alloc((size_t)H_*FF_*2);
  bf16*  wft  = (bf16*) alloc((size_t)H_*FF_*2);
  float* qkbias=(float*)alloc((size_t)QKV_*4);
  bf16*  hb   = (bf16*) alloc((size_t)M_*H_*2);
  float* h32  = (float*)alloc((size_t)M_*H_*4);
  float* a32  = (float*)alloc((size_t)M_*H_*4);
  float* tmp  = (float*)alloc((size_t)M_*H_*4);
  bf16*  qkvb = (bf16*) alloc((size_t)M_*QKV_*2);   // packed q|k|v activations
  bf16*  cxb  = (bf16*) alloc((size_t)M_*H_*2);
  bf16*  inb  = (bf16*) alloc((size_t)M_*FF_*2);

  embed_ln<<<M_, 256, 0, stream>>>(ids, we, pe, te, les, leb, h32, hb);

  for (int l = 0; l < L_; ++l) {
    size_t wsq = (size_t)l*H_*H_;
    transpose_w<<<dim3(H_/64,  H_/64 ), 256, 0, stream>>>(Wq + wsq, wqkv,            H_, H_);
    transpose_w<<<dim3(H_/64,  H_/64 ), 256, 0, stream>>>(Wk + wsq, wqkv + 768*768,  H_, H_);
    transpose_w<<<dim3(H_/64,  H_/64 ), 256, 0, stream>>>(Wv + wsq, wqkv + 2*768*768,H_, H_);
    transpose_w<<<dim3(H_/64,  H_/64 ), 256, 0, stream>>>(Wo + wsq, wot, H_, H_);
    transpose_w<<<dim3(H_/64,  FF_/64), 256, 0, stream>>>(Wi + (size_t)l*H_*FF_, wit, H_, FF_);
    transpose_w<<<dim3(FF_/64, H_/64 ), 256, 0, stream>>>(Wf + (size_t)l*FF_*H_, wft, FF_, H_);
    pack_qkv_bias<<<QKV_/256, 256, 0, stream>>>(bq + l*H_, bk + l*H_, bv + l*H_, qkbias);

    gemm256<<<64*(QKV_/256), 512, 0, stream>>>(hb,  wqkv, qkbias,      qkvb, QKV_, H_,  QKV_/256, 0);
    attn_kernel<<<B_*NH_*2, 256, 0, stream>>>(qkvb, mask, cxb);
    gemm256<<<64*(H_/256),  512, 0, stream>>>(cxb, wot, bo  + l*H_,  tmp,  H_,  H_,  H_/256,  1);
    ln_res<<<M_, 256, 0, stream>>>(tmp, h32, l1s + l*H_, l1b + l*H_, a32, hb);
    gemm256<<<64*(FF_/256), 512, 0, stream>>>(hb,  wit, bi  + l*FF_, inb,  FF_, H_,  FF_/256, 2);
    gemm256<<<64*(H_/256),  512, 0, stream>>>(inb, wft, bfp + l*H_,  tmp,  H_,  FF_, H_/256,  1);
    ln_res<<<M_, 256, 0, stream>>>(tmp, a32, l2s + l*H_, l2b + l*H_, h32, hb);
  }

  pool_norm<<<B_, 256, 0, stream>>>(h32, mask, (float*)d_out);
}

// Round 3
// 7138.349 us; speedup vs baseline: 1.3226x; 1.1120x over previous
//
#include <hip/hip_runtime.h>
#include <hip/hip_bf16.h>
#include <math.h>

typedef __bf16 bf16;
typedef __bf16 bf16x8 __attribute__((ext_vector_type(8)));
typedef float  f32x4  __attribute__((ext_vector_type(4)));

#define B_  32
#define S_  512
#define H_  768
#define NH_ 12
#define DH_ 64
#define FF_ 3072
#define L_  12
#define M_  (B_*S_)
#define QKV_ 2304   // packed q|k|v row stride

// padded LDS strides (bank-conflict fix: +4 elems = 2-bank row rotation)
#define KST 68      // K tile row stride (bf16)
#define VST 516     // V^T tile row stride (bf16)
#define PST 68      // P tile row stride (bf16)

// ---- async global->LDS, 16B per lane; lds base must be wave-uniform ----
__device__ __forceinline__ void gload16(const bf16* g, bf16* l) {
  __builtin_amdgcn_global_load_lds(
      (const __attribute__((address_space(1))) void*)g,
      (__attribute__((address_space(3))) void*)l, 16, 0, 0);
}

// =================== 256x256 8-phase GEMM ===================
// C[M,N] = A[M,K] * Bt[N,K]^T + bias.  epi: 0 bf16, 1 f32, 2 gelu->bf16
__global__ __launch_bounds__(512, 2) void gemm256(
    const bf16* __restrict__ A, const bf16* __restrict__ Bt,
    const float* __restrict__ bias, void* __restrict__ outp,
    int N, int K, int tiles_n, int epi)
{
  __shared__ bf16 sm[2][2][256*64];   // [buf][A|B][row*64 + col] : 128 KB
  const int tid  = threadIdx.x;
  const int lane = tid & 63, wid = tid >> 6;
  const int wr = wid >> 2, wc = wid & 3;          // 2 x 4 wave grid
  const int lrow = lane & 15, kgrp = lane >> 4;

  // bijective XCD swizzle (m204)
  const int nwg = gridDim.x, orig = blockIdx.x;
  const int qc = nwg >> 3, rc = nwg & 7;
  const int xcd = orig & 7, lin = orig >> 3;
  const int wg = (xcd < rc ? xcd*(qc+1) : rc*(qc+1) + (xcd-rc)*qc) + lin;
  const int tm = wg / tiles_n, tn = wg % tiles_n;
  const size_t m0 = (size_t)tm * 256, n0 = (size_t)tn * 256;
  const int KT = K >> 6;

  const bf16* Ab = A  + m0 * K;
  const bf16* Bb = Bt + n0 * K;

  auto stage_half = [&](int buf, int ab, int row0, const bf16* gbase, int kt) {
#pragma unroll
    for (int j = 0; j < 2; ++j) {
      int lin2  = j*512 + tid;
      int prow  = lin2 >> 3;
      int pslot = lin2 & 7;
      int lslot = pslot ^ (prow & 7);
      const bf16* src = gbase + (size_t)(row0 + prow) * K + (size_t)kt*64 + lslot*8;
      bf16* dst = &sm[buf][ab][row0*64 + (j*512 + (wid<<6))*8];
      gload16(src, dst);
    }
  };

  f32x4 acc[2][2][4][2] = {};

  stage_half(0, 0, 0,   Ab, 0);
  stage_half(0, 1, 0,   Bb, 0);
  stage_half(0, 0, 128, Ab, 0);
  stage_half(0, 1, 128, Bb, 0);
  stage_half(1, 0, 0,   Ab, 1);
  stage_half(1, 1, 0,   Bb, 1);
  asm volatile("s_waitcnt vmcnt(8)" ::: "memory");
  __builtin_amdgcn_s_barrier();

#define PHASE(MH, NH, ISSUE, WAITV)                                           \
  {                                                                           \
    bf16x8 af[4][2], bfv[2][2];                                               \
    _Pragma("unroll") for (int m = 0; m < 4; ++m)                             \
      _Pragma("unroll") for (int kk = 0; kk < 2; ++kk) {                      \
        int row  = MH*128 + wr*64 + m*16 + lrow;                              \
        int slot = (kk*4 + kgrp) ^ (lrow & 7);                                \
        af[m][kk] = *(const bf16x8*)&As[row*64 + slot*8];                     \
      }                                                                       \
    _Pragma("unroll") for (int n = 0; n < 2; ++n)                             \
      _Pragma("unroll") for (int kk = 0; kk < 2; ++kk) {                      \
        int row  = NH*128 + wc*32 + n*16 + lrow;                              \
        int slot = (kk*4 + kgrp) ^ (lrow & 7);                                \
        bfv[n][kk] = *(const bf16x8*)&Bs[row*64 + slot*8];                    \
      }                                                                       \
    ISSUE;                                                                    \
    __builtin_amdgcn_s_barrier();                                             \
    asm volatile("s_waitcnt lgkmcnt(0)" ::: "memory");                        \
    __builtin_amdgcn_sched_barrier(0);                                        \
    __builtin_amdgcn_s_setprio(1);                                            \
    _Pragma("unroll") for (int kk = 0; kk < 2; ++kk)                          \
      _Pragma("unroll") for (int m = 0; m < 4; ++m)                           \
        _Pragma("unroll") for (int n = 0; n < 2; ++n)                         \
          acc[MH][NH][m][n] = __builtin_amdgcn_mfma_f32_16x16x32_bf16(        \
              af[m][kk], bfv[n][kk], acc[MH][NH][m][n], 0, 0, 0);             \
    __builtin_amdgcn_s_setprio(0);                                            \
    WAITV;                                                                    \
    __builtin_amdgcn_s_barrier();                                             \
  }

  for (int t = 0; t < KT; ++t) {
    const int cur = t & 1;
    bf16* As = sm[cur][0];
    bf16* Bs = sm[cur][1];
    const int t1 = (t+1 < KT) ? t+1 : KT-1;
    const int t2 = (t+2 < KT) ? t+2 : KT-1;
    const int b1 = (t+1) & 1, b2 = t & 1;

    PHASE(0, 0,
          stage_half(b1, 0, 128, Ab, t1),
          asm volatile("s_waitcnt vmcnt(6)" ::: "memory"));
    PHASE(0, 1,
          stage_half(b1, 1, 128, Bb, t1), );
    PHASE(1, 0,
          stage_half(b2, 0, 0, Ab, t2), );
    PHASE(1, 1,
          stage_half(b2, 1, 0, Bb, t2),
          asm volatile("s_waitcnt vmcnt(8)" ::: "memory"));
  }
#undef PHASE

#pragma unroll
  for (int mh = 0; mh < 2; ++mh)
#pragma unroll
    for (int nh = 0; nh < 2; ++nh)
#pragma unroll
      for (int n = 0; n < 2; ++n) {
        int col = (int)n0 + nh*128 + wc*32 + n*16 + lrow;
        float bv = bias[col];
#pragma unroll
        for (int m = 0; m < 4; ++m)
#pragma unroll
          for (int r = 0; r < 4; ++r) {
            int row = (int)m0 + mh*128 + wr*64 + m*16 + kgrp*4 + r;
            float x = acc[mh][nh][m][n][r] + bv;
            size_t idx = (size_t)row * N + col;
            if (epi == 1)      ((float*)outp)[idx] = x;
            else if (epi == 0) ((bf16*)outp)[idx]  = (bf16)x;
            else               ((bf16*)outp)[idx]  = (bf16)(0.5f * x * (1.0f + erff(x * 0.70710678118f)));
          }
      }
}

// ---------------- weight transpose + fp32->bf16 ----------------
__global__ __launch_bounds__(256) void transpose_w(
    const float* __restrict__ W, bf16* __restrict__ Wt, int K, int N)
{
  __shared__ bf16 T[64][65];
  int k0 = blockIdx.x * 64, n0 = blockIdx.y * 64;
  int tx = threadIdx.x & 63, ty = threadIdx.x >> 6;
#pragma unroll
  for (int j = 0; j < 16; ++j) {
    int kk = j*4 + ty;
    T[kk][tx] = (bf16)W[(size_t)(k0+kk)*N + n0 + tx];
  }
  __syncthreads();
#pragma unroll
  for (int j = 0; j < 16; ++j) {
    int nn = j*4 + ty;
    Wt[(size_t)(n0+nn)*K + k0 + tx] = T[tx][nn];
  }
}

__global__ __launch_bounds__(256) void pack_qkv_bias(
    const float* __restrict__ bq, const float* __restrict__ bk,
    const float* __restrict__ bv, float* __restrict__ out)
{
  int i = blockIdx.x*256 + threadIdx.x;
  out[i] = (i < 768) ? bq[i] : (i < 1536 ? bk[i-768] : bv[i-1536]);
}

// ---------------- block reductions ----------------
__device__ __forceinline__ void block_sum2(float& a, float& b, float* red) {
  int lane = threadIdx.x & 63, wid = threadIdx.x >> 6;
  for (int o = 32; o > 0; o >>= 1) { a += __shfl_xor(a, o); b += __shfl_xor(b, o); }
  if (lane == 0) { red[wid*2] = a; red[wid*2+1] = b; }
  __syncthreads();
  a = red[0] + red[2] + red[4] + red[6];
  b = red[1] + red[3] + red[5] + red[7];
  __syncthreads();
}

// ---------------- embedding + LN ----------------
__global__ __launch_bounds__(256) void embed_ln(
    const int* __restrict__ ids, const float* __restrict__ we,
    const float* __restrict__ pe, const float* __restrict__ te,
    const float* __restrict__ gs, const float* __restrict__ gb,
    float* __restrict__ h32, bf16* __restrict__ hb)
{
  __shared__ float red[8];
  int row = blockIdx.x;
  int s = row & (S_-1);
  int id = ids[row];
  int t = threadIdx.x;
  float x[3], sum = 0.f, sq = 0.f;
#pragma unroll
  for (int j = 0; j < 3; ++j) {
    int c = t + j*256;
    float v = we[(size_t)id*H_ + c] + pe[(size_t)s*H_ + c] + te[c];
    x[j] = v; sum += v; sq += v*v;
  }
  block_sum2(sum, sq, red);
  float mean = sum * (1.f/H_);
  float var  = sq  * (1.f/H_) - mean*mean;
  float rstd = rsqrtf(fmaxf(var, 0.f) + 1e-12f);
#pragma unroll
  for (int j = 0; j < 3; ++j) {
    int c = t + j*256;
    float y = (x[j]-mean)*rstd*gs[c] + gb[c];
    h32[(size_t)row*H_ + c] = y;
    hb [(size_t)row*H_ + c] = (bf16)y;
  }
}

// ---------------- residual add + LN ----------------
__global__ __launch_bounds__(256) void ln_res(
    const float* __restrict__ t32, const float* __restrict__ res,
    const float* __restrict__ gs, const float* __restrict__ gb,
    float* __restrict__ o32, bf16* __restrict__ ob)
{
  __shared__ float red[8];
  int row = blockIdx.x, t = threadIdx.x;
  float x[3], sum = 0.f, sq = 0.f;
#pragma unroll
  for (int j = 0; j < 3; ++j) {
    int c = t + j*256;
    float v = t32[(size_t)row*H_ + c] + res[(size_t)row*H_ + c];
    x[j] = v; sum += v; sq += v*v;
  }
  block_sum2(sum, sq, red);
  float mean = sum * (1.f/H_);
  float var  = sq  * (1.f/H_) - mean*mean;
  float rstd = rsqrtf(fmaxf(var, 0.f) + 1e-12f);
#pragma unroll
  for (int j = 0; j < 3; ++j) {
    int c = t + j*256;
    float y = (x[j]-mean)*rstd*gs[c] + gb[c];
    o32[(size_t)row*H_ + c] = y;
    ob [(size_t)row*H_ + c] = (bf16)y;
  }
}

// ---------------- fused attention: 512 threads, padded LDS ----------------
// block = (b, head, half): 256 q rows; 8 waves -> 2 passes x 128 q rows
__global__ __launch_bounds__(512, 2) void attn_kernel(
    const bf16* __restrict__ qkv, const float* __restrict__ mask,
    bf16* __restrict__ ctx)
{
  __shared__ bf16 Kl[S_*KST];      // 69632 B
  __shared__ bf16 Vt[DH_*VST];     // 66048 B
  __shared__ float mk[S_];         //  2048 B
  __shared__ bf16 Pl[8][16*PST];   // 17408 B   total 155136 B
  int bid = blockIdx.x;
  int half = bid & 1, bh = bid >> 1;
  int h = bh % NH_, b = bh / NH_;
  int tid = threadIdx.x, lane = tid & 63, wid = tid >> 6;
  int lrow = lane & 15, kgrp = lane >> 4;
  const bf16* Qb = qkv + (size_t)(b*S_)*QKV_        + h*DH_;
  const bf16* Kb = qkv + (size_t)(b*S_)*QKV_ + H_   + h*DH_;
  const bf16* Vb = qkv + (size_t)(b*S_)*QKV_ + 2*H_ + h*DH_;

  // stage K row-major (padded) + V transposed (padded)
  for (int it = 0; it < 8; ++it) {
    int slot = it*512 + tid;
    int s = slot >> 3, c8 = (slot & 7)*8;
    *(bf16x8*)&Kl[s*KST + c8] = *(const bf16x8*)&Kb[(size_t)s*QKV_ + c8];
    bf16x8 v = *(const bf16x8*)&Vb[(size_t)s*QKV_ + c8];
#pragma unroll
    for (int i = 0; i < 8; ++i) Vt[(c8+i)*VST + s] = v[i];
  }
  mk[tid] = mask[b*S_ + tid];
  __syncthreads();

  for (int pass = 0; pass < 2; ++pass) {
    int q0 = half*256 + pass*128 + wid*16;
    bf16x8 qa[2];
#pragma unroll
    for (int kc = 0; kc < 2; ++kc)
      qa[kc] = *(const bf16x8*)&Qb[(size_t)(q0 + lrow)*QKV_ + kc*32 + kgrp*8];
    f32x4 O[4] = {};
    float mrun[4], lrun[4];
#pragma unroll
    for (int r = 0; r < 4; ++r) { mrun[r] = -1e30f; lrun[r] = 0.f; }

    for (int c0 = 0; c0 < S_; c0 += 64) {
      f32x4 Sf[4] = {};
      __builtin_amdgcn_s_setprio(1);
#pragma unroll
      for (int kc = 0; kc < 2; ++kc)
#pragma unroll
        for (int sn = 0; sn < 4; ++sn) {
          bf16x8 kbv = *(const bf16x8*)&Kl[(c0 + sn*16 + lrow)*KST + kc*32 + kgrp*8];
          Sf[sn] = __builtin_amdgcn_mfma_f32_16x16x32_bf16(qa[kc], kbv, Sf[sn], 0, 0, 0);
        }
      __builtin_amdgcn_s_setprio(0);
      float cmax[4];
#pragma unroll
      for (int r = 0; r < 4; ++r) cmax[r] = -1e30f;
#pragma unroll
      for (int sn = 0; sn < 4; ++sn)
#pragma unroll
        for (int r = 0; r < 4; ++r) {
          Sf[sn][r] *= 0.125f;
          cmax[r] = fmaxf(cmax[r], Sf[sn][r]);
        }
      for (int o = 1; o < 16; o <<= 1)
#pragma unroll
        for (int r = 0; r < 4; ++r) cmax[r] = fmaxf(cmax[r], __shfl_xor(cmax[r], o));
      float newm[4], fr[4], lsum[4];
#pragma unroll
      for (int r = 0; r < 4; ++r) {
        newm[r] = fmaxf(mrun[r], cmax[r]);
        fr[r]   = __expf(mrun[r] - newm[r]);
        lsum[r] = 0.f;
      }
#pragma unroll
      for (int sn = 0; sn < 4; ++sn) {
        float mkv = mk[c0 + sn*16 + lrow];
#pragma unroll
        for (int r = 0; r < 4; ++r) {
          float e = __expf(Sf[sn][r] - newm[r]) * mkv;
          bf16 eb = (bf16)e;
          lsum[r] += (float)eb;
          Pl[wid][(kgrp*4 + r)*PST + sn*16 + lrow] = eb;
        }
      }
      for (int o = 1; o < 16; o <<= 1)
#pragma unroll
        for (int r = 0; r < 4; ++r) lsum[r] += __shfl_xor(lsum[r], o);
#pragma unroll
      for (int r = 0; r < 4; ++r) { lrun[r] = lrun[r]*fr[r] + lsum[r]; mrun[r] = newm[r]; }
#pragma unroll
      for (int on = 0; on < 4; ++on)
#pragma unroll
        for (int r = 0; r < 4; ++r) O[on][r] *= fr[r];
      asm volatile("s_waitcnt lgkmcnt(0)" ::: "memory");
      __builtin_amdgcn_sched_barrier(0);
      __builtin_amdgcn_s_setprio(1);
#pragma unroll
      for (int kc = 0; kc < 2; ++kc) {
        bf16x8 pa = *(const bf16x8*)&Pl[wid][lrow*PST + kc*32 + kgrp*8];
#pragma unroll
        for (int on = 0; on < 4; ++on) {
          bf16x8 vv = *(const bf16x8*)&Vt[(on*16 + lrow)*VST + c0 + kc*32 + kgrp*8];
          O[on] = __builtin_amdgcn_mfma_f32_16x16x32_bf16(pa, vv, O[on], 0, 0, 0);
        }
      }
      __builtin_amdgcn_s_setprio(0);
    }
#pragma unroll
    for (int on = 0; on < 4; ++on)
#pragma unroll
      for (int r = 0; r < 4; ++r) {
        float val = O[on][r] / fmaxf(lrun[r], 1e-9f);
        int q = q0 + kgrp*4 + r;
        ctx[(size_t)(b*S_ + q)*H_ + h*DH_ + on*16 + lrow] = (bf16)val;
      }
  }
}

// ---------------- masked mean pool + L2 normalize ----------------
__global__ __launch_bounds__(256) void pool_norm(
    const float* __restrict__ h32, const float* __restrict__ mask,
    float* __restrict__ out)
{
  __shared__ float red[8];
  int b = blockIdx.x, t = threadIdx.x;
  float a0 = 0.f, a1 = 0.f, a2 = 0.f;
  for (int s = 0; s < S_; ++s) {
    float m = mask[b*S_ + s];
    const float* hp = &h32[((size_t)b*S_ + s)*H_];
    a0 += hp[t]*m; a1 += hp[t+256]*m; a2 += hp[t+512]*m;
  }
  float msum = mask[b*S_ + t] + mask[b*S_ + 256 + t];
  float dummy = 0.f;
  block_sum2(msum, dummy, red);
  float inv = 1.f / fmaxf(msum, 1e-6f);
  float s0 = a0*inv, s1 = a1*inv, s2 = a2*inv;
  float nrm = s0*s0 + s1*s1 + s2*s2;
  dummy = 0.f;
  block_sum2(nrm, dummy, red);
  float rn = 1.f / fmaxf(sqrtf(nrm), 1e-12f);
  out[b*H_ + t]       = s0*rn;
  out[b*H_ + t + 256] = s1*rn;
  out[b*H_ + t + 512] = s2*rn;
}

// ---------------- host driver ----------------
extern "C" void kernel_launch(void* const* d_in, const int* in_sizes, int n_in,
                              void* d_out, int out_size, void* d_ws, size_t ws_size,
                              hipStream_t stream)
{
  const int*   ids  = (const int*)  d_in[0];
  const float* mask = (const float*)d_in[1];
  const float* we   = (const float*)d_in[2];
  const float* pe   = (const float*)d_in[3];
  const float* te   = (const float*)d_in[4];
  const float* les  = (const float*)d_in[5];
  const float* leb  = (const float*)d_in[6];
  const float* Wq   = (const float*)d_in[7];
  const float* bq   = (const float*)d_in[8];
  const float* Wk   = (const float*)d_in[9];
  const float* bk   = (const float*)d_in[10];
  const float* Wv   = (const float*)d_in[11];
  const float* bv   = (const float*)d_in[12];
  const float* Wo   = (const float*)d_in[13];
  const float* bo   = (const float*)d_in[14];
  const float* l1s  = (const float*)d_in[15];
  const float* l1b  = (const float*)d_in[16];
  const float* Wi   = (const float*)d_in[17];
  const float* bi   = (const float*)d_in[18];
  const float* Wf   = (const float*)d_in[19];
  const float* bfp  = (const float*)d_in[20];
  const float* l2s  = (const float*)d_in[21];
  const float* l2b  = (const float*)d_in[22];

  char* p = (char*)d_ws;
  auto alloc = [&](size_t bytes) { char* q = p; p += (bytes + 255) & ~(size_t)255; return q; };
  bf16*  wqkv = (bf16*) alloc((size_t)QKV_*H_*2);
  bf16*  wot  = (bf16*) alloc((size_t)H_*H_*2);
  bf16*  wit  = (bf16*) alloc((size_t)H_*FF_*2);
  bf16*  wft  = (bf16*) alloc((size_t)H_*FF_*2);
  float* qkbias=(float*)alloc((size_t)QKV_*4);
  bf16*  hb   = (bf16*) alloc((size_t)M_*H_*2);
  float* h32  = (float*)alloc((size_t)M_*H_*4);
  float* a32  = (float*)alloc((size_t)M_*H_*4);
  float* tmp  = (float*)alloc((size_t)M_*H_*4);
  bf16*  qkvb = (bf16*) alloc((size_t)M_*QKV_*2);
  bf16*  cxb  = (bf16*) alloc((size_t)M_*H_*2);
  bf16*  inb  = (bf16*) alloc((size_t)M_*FF_*2);

  embed_ln<<<M_, 256, 0, stream>>>(ids, we, pe, te, les, leb, h32, hb);

  for (int l = 0; l < L_; ++l) {
    size_t wsq = (size_t)l*H_*H_;
    transpose_w<<<dim3(H_/64,  H_/64 ), 256, 0, stream>>>(Wq + wsq, wqkv,            H_, H_);
    transpose_w<<<dim3(H_/64,  H_/64 ), 256, 0, stream>>>(Wk + wsq, wqkv + 768*768,  H_, H_);
    transpose_w<<<dim3(H_/64,  H_/64 ), 256, 0, stream>>>(Wv + wsq, wqkv + 2*768*768,H_, H_);
    transpose_w<<<dim3(H_/64,  H_/64 ), 256, 0, stream>>>(Wo + wsq, wot, H_, H_);
    transpose_w<<<dim3(H_/64,  FF_/64), 256, 0, stream>>>(Wi + (size_t)l*H_*FF_, wit, H_, FF_);
    transpose_w<<<dim3(FF_/64, H_/64 ), 256, 0, stream>>>(Wf + (size_t)l*FF_*H_, wft, FF_, H_);
    pack_qkv_bias<<<QKV_/256, 256, 0, stream>>>(bq + l*H_, bk + l*H_, bv + l*H_, qkbias);

    gemm256<<<64*(QKV_/256), 512, 0, stream>>>(hb,  wqkv, qkbias,      qkvb, QKV_, H_,  QKV_/256, 0);
    attn_kernel<<<B_*NH_*2, 512, 0, stream>>>(qkvb, mask, cxb);
    gemm256<<<64*(H_/256),  512, 0, stream>>>(cxb, wot, bo  + l*H_,  tmp,  H_,  H_,  H_/256,  1);
    ln_res<<<M_, 256, 0, stream>>>(tmp, h32, l1s + l*H_, l1b + l*H_, a32, hb);
    gemm256<<<64*(FF_/256), 512, 0, stream>>>(hb,  wit, bi  + l*FF_, inb,  FF_, H_,  FF_/256, 2);
    gemm256<<<64*(H_/256),  512, 0, stream>>>(inb, wft, bfp + l*H_,  tmp,  H_,  FF_, H_/256,  1);
    ln_res<<<M_, 256, 0, stream>>>(tmp, a32, l2s + l*H_, l2b + l*H_, h32, hb);
  }

  pool_norm<<<B_, 256, 0, stream>>>(h32, mask, (float*)d_out);
}

// Round 4
// 6741.475 us; speedup vs baseline: 1.4004x; 1.0589x over previous
//
#include <hip/hip_runtime.h>
#include <hip/hip_bf16.h>
#include <math.h>

typedef __bf16 bf16;
typedef __bf16 bf16x8 __attribute__((ext_vector_type(8)));
typedef float  f32x4  __attribute__((ext_vector_type(4)));

#define B_  32
#define S_  512
#define H_  768
#define NH_ 12
#define DH_ 64
#define FF_ 3072
#define L_  12
#define M_  (B_*S_)
#define QKV_ 2304   // packed q|k|v row stride

// padded LDS strides (attention bank-conflict fix)
#define KST 68
#define VST 516
#define PST 68

// ---- async global->LDS, 16B per lane; lds base must be wave-uniform ----
__device__ __forceinline__ void gload16(const bf16* g, bf16* l) {
  __builtin_amdgcn_global_load_lds(
      (const __attribute__((address_space(1))) void*)g,
      (__attribute__((address_space(3))) void*)l, 16, 0, 0);
}

// =================== 256x256 8-phase GEMM (snake quadrant order) ===================
// C[M,N] = A[M,K] * Bt[N,K]^T + bias.  epi: 0 bf16, 1 f32, 2 gelu->bf16
// Per K-tile ds_reads minimized: p0 loads A0+B0 (12xb128), p1 B1 (4), p2 A1 (8), p3 none.
__global__ __launch_bounds__(512, 2) void gemm256(
    const bf16* __restrict__ A, const bf16* __restrict__ Bt,
    const float* __restrict__ bias, void* __restrict__ outp,
    int N, int K, int tiles_n, int epi)
{
  __shared__ bf16 sm[2][2][256*64];   // [buf][A|B][row*64 + col] : 128 KB
  const int tid  = threadIdx.x;
  const int lane = tid & 63, wid = tid >> 6;
  const int wr = wid >> 2, wc = wid & 3;          // 2 x 4 wave grid
  const int lrow = lane & 15, kgrp = lane >> 4;

  // bijective XCD swizzle (m204)
  const int nwg = gridDim.x, orig = blockIdx.x;
  const int qc = nwg >> 3, rc = nwg & 7;
  const int xcd = orig & 7, lin = orig >> 3;
  const int wg = (xcd < rc ? xcd*(qc+1) : rc*(qc+1) + (xcd-rc)*qc) + lin;
  const int tm = wg / tiles_n, tn = wg % tiles_n;
  const size_t m0 = (size_t)tm * 256, n0 = (size_t)tn * 256;
  const int KT = K >> 6;

  const bf16* Ab = A  + m0 * K;
  const bf16* Bb = Bt + n0 * K;

  auto stage_half = [&](int buf, int ab, int row0, const bf16* gbase, int kt) {
#pragma unroll
    for (int j = 0; j < 2; ++j) {
      int lin2  = j*512 + tid;
      int prow  = lin2 >> 3;
      int pslot = lin2 & 7;
      int lslot = pslot ^ (prow & 7);
      const bf16* src = gbase + (size_t)(row0 + prow) * K + (size_t)kt*64 + lslot*8;
      bf16* dst = &sm[buf][ab][row0*64 + (j*512 + (wid<<6))*8];
      gload16(src, dst);
    }
  };

  // fragment loaders (swizzled read)
  auto loadA = [&](bf16* As, int MH, bf16x8 (&af)[4][2]) {
#pragma unroll
    for (int m = 0; m < 4; ++m)
#pragma unroll
      for (int kk = 0; kk < 2; ++kk) {
        int row  = MH*128 + wr*64 + m*16 + lrow;
        int slot = (kk*4 + kgrp) ^ (lrow & 7);
        af[m][kk] = *(const bf16x8*)&As[row*64 + slot*8];
      }
  };
  auto loadB = [&](bf16* Bs, int NHq, bf16x8 (&bfv)[2][2]) {
#pragma unroll
    for (int n = 0; n < 2; ++n)
#pragma unroll
      for (int kk = 0; kk < 2; ++kk) {
        int row  = NHq*128 + wc*32 + n*16 + lrow;
        int slot = (kk*4 + kgrp) ^ (lrow & 7);
        bfv[n][kk] = *(const bf16x8*)&Bs[row*64 + slot*8];
      }
  };

  f32x4 acc[2][2][4][2] = {};

  // ---- prologue: tile0 full -> buf0, tile1 half0 -> buf1 : 12 loads
  stage_half(0, 0, 0,   Ab, 0);
  stage_half(0, 1, 0,   Bb, 0);
  stage_half(0, 0, 128, Ab, 0);
  stage_half(0, 1, 128, Bb, 0);
  stage_half(1, 0, 0,   Ab, 1);
  stage_half(1, 1, 0,   Bb, 1);
  asm volatile("s_waitcnt vmcnt(8)" ::: "memory");   // retire tile0 A0,B0
  __builtin_amdgcn_s_barrier();

#define MFMA16(MH, NHq, AF, BF)                                               \
    __builtin_amdgcn_s_barrier();                                             \
    asm volatile("s_waitcnt lgkmcnt(0)" ::: "memory");                        \
    __builtin_amdgcn_sched_barrier(0);                                        \
    __builtin_amdgcn_s_setprio(1);                                            \
    _Pragma("unroll") for (int kk = 0; kk < 2; ++kk)                          \
      _Pragma("unroll") for (int m = 0; m < 4; ++m)                           \
        _Pragma("unroll") for (int n = 0; n < 2; ++n)                         \
          acc[MH][NHq][m][n] = __builtin_amdgcn_mfma_f32_16x16x32_bf16(       \
              AF[m][kk], BF[n][kk], acc[MH][NHq][m][n], 0, 0, 0);             \
    __builtin_amdgcn_s_setprio(0);

  for (int t = 0; t < KT; ++t) {
    bf16* As = sm[t&1][0];
    bf16* Bs = sm[t&1][1];
    const int t1 = (t+1 < KT) ? t+1 : KT-1;
    const int t2 = (t+2 < KT) ? t+2 : KT-1;
    const int b1 = (t+1) & 1, b2 = t & 1;

    bf16x8 af[4][2], bv0[2][2], bv1[2][2];

    // p0 (0,0): read A0,B0; issue A1(t+1); retire A1(t),B1(t)
    loadA(As, 0, af);
    loadB(Bs, 0, bv0);
    stage_half(b1, 0, 128, Ab, t1);
    MFMA16(0, 0, af, bv0);
    asm volatile("s_waitcnt vmcnt(6)" ::: "memory");
    __builtin_amdgcn_s_barrier();

    // p1 (0,1): read B1; issue B1(t+1)
    loadB(Bs, 1, bv1);
    stage_half(b1, 1, 128, Bb, t1);
    MFMA16(0, 1, af, bv1);
    __builtin_amdgcn_s_barrier();

    // p2 (1,1): read A1; issue A0(t+2) into cur (half0 dead after p0)
    loadA(As, 1, af);
    stage_half(b2, 0, 0, Ab, t2);
    MFMA16(1, 1, af, bv1);
    __builtin_amdgcn_s_barrier();

    // p3 (1,0): no reads; issue B0(t+2); retire A0(t+1),B0(t+1)
    stage_half(b2, 1, 0, Bb, t2);
    MFMA16(1, 0, af, bv0);
    asm volatile("s_waitcnt vmcnt(8)" ::: "memory");
    __builtin_amdgcn_s_barrier();
  }
#undef MFMA16

#pragma unroll
  for (int mh = 0; mh < 2; ++mh)
#pragma unroll
    for (int nh = 0; nh < 2; ++nh)
#pragma unroll
      for (int n = 0; n < 2; ++n) {
        int col = (int)n0 + nh*128 + wc*32 + n*16 + lrow;
        float bv = bias[col];
#pragma unroll
        for (int m = 0; m < 4; ++m)
#pragma unroll
          for (int r = 0; r < 4; ++r) {
            int row = (int)m0 + mh*128 + wr*64 + m*16 + kgrp*4 + r;
            float x = acc[mh][nh][m][n][r] + bv;
            size_t idx = (size_t)row * N + col;
            if (epi == 1)      ((float*)outp)[idx] = x;
            else if (epi == 0) ((bf16*)outp)[idx]  = (bf16)x;
            else               ((bf16*)outp)[idx]  = (bf16)(0.5f * x * (1.0f + erff(x * 0.70710678118f)));
          }
      }
}

// ---------------- weight transpose + fp32->bf16 ----------------
__global__ __launch_bounds__(256) void transpose_w(
    const float* __restrict__ W, bf16* __restrict__ Wt, int K, int N)
{
  __shared__ bf16 T[64][65];
  int k0 = blockIdx.x * 64, n0 = blockIdx.y * 64;
  int tx = threadIdx.x & 63, ty = threadIdx.x >> 6;
#pragma unroll
  for (int j = 0; j < 16; ++j) {
    int kk = j*4 + ty;
    T[kk][tx] = (bf16)W[(size_t)(k0+kk)*N + n0 + tx];
  }
  __syncthreads();
#pragma unroll
  for (int j = 0; j < 16; ++j) {
    int nn = j*4 + ty;
    Wt[(size_t)(n0+nn)*K + k0 + tx] = T[tx][nn];
  }
}

__global__ __launch_bounds__(256) void pack_qkv_bias(
    const float* __restrict__ bq, const float* __restrict__ bk,
    const float* __restrict__ bv, float* __restrict__ out)
{
  int i = blockIdx.x*256 + threadIdx.x;
  out[i] = (i < 768) ? bq[i] : (i < 1536 ? bk[i-768] : bv[i-1536]);
}

// ---------------- block reductions ----------------
__device__ __forceinline__ void block_sum2(float& a, float& b, float* red) {
  int lane = threadIdx.x & 63, wid = threadIdx.x >> 6;
  for (int o = 32; o > 0; o >>= 1) { a += __shfl_xor(a, o); b += __shfl_xor(b, o); }
  if (lane == 0) { red[wid*2] = a; red[wid*2+1] = b; }
  __syncthreads();
  a = red[0] + red[2] + red[4] + red[6];
  b = red[1] + red[3] + red[5] + red[7];
  __syncthreads();
}

// ---------------- embedding + LN ----------------
__global__ __launch_bounds__(256) void embed_ln(
    const int* __restrict__ ids, const float* __restrict__ we,
    const float* __restrict__ pe, const float* __restrict__ te,
    const float* __restrict__ gs, const float* __restrict__ gb,
    float* __restrict__ h32, bf16* __restrict__ hb)
{
  __shared__ float red[8];
  int row = blockIdx.x;
  int s = row & (S_-1);
  int id = ids[row];
  int t = threadIdx.x;
  float x[3], sum = 0.f, sq = 0.f;
#pragma unroll
  for (int j = 0; j < 3; ++j) {
    int c = t + j*256;
    float v = we[(size_t)id*H_ + c] + pe[(size_t)s*H_ + c] + te[c];
    x[j] = v; sum += v; sq += v*v;
  }
  block_sum2(sum, sq, red);
  float mean = sum * (1.f/H_);
  float var  = sq  * (1.f/H_) - mean*mean;
  float rstd = rsqrtf(fmaxf(var, 0.f) + 1e-12f);
#pragma unroll
  for (int j = 0; j < 3; ++j) {
    int c = t + j*256;
    float y = (x[j]-mean)*rstd*gs[c] + gb[c];
    h32[(size_t)row*H_ + c] = y;
    hb [(size_t)row*H_ + c] = (bf16)y;
  }
}

// ---------------- residual add + LN ----------------
__global__ __launch_bounds__(256) void ln_res(
    const float* __restrict__ t32, const float* __restrict__ res,
    const float* __restrict__ gs, const float* __restrict__ gb,
    float* __restrict__ o32, bf16* __restrict__ ob)
{
  __shared__ float red[8];
  int row = blockIdx.x, t = threadIdx.x;
  float x[3], sum = 0.f, sq = 0.f;
#pragma unroll
  for (int j = 0; j < 3; ++j) {
    int c = t + j*256;
    float v = t32[(size_t)row*H_ + c] + res[(size_t)row*H_ + c];
    x[j] = v; sum += v; sq += v*v;
  }
  block_sum2(sum, sq, red);
  float mean = sum * (1.f/H_);
  float var  = sq  * (1.f/H_) - mean*mean;
  float rstd = rsqrtf(fmaxf(var, 0.f) + 1e-12f);
#pragma unroll
  for (int j = 0; j < 3; ++j) {
    int c = t + j*256;
    float y = (x[j]-mean)*rstd*gs[c] + gb[c];
    o32[(size_t)row*H_ + c] = y;
    ob [(size_t)row*H_ + c] = (bf16)y;
  }
}

// ---------------- fused attention: 512 threads, padded LDS ----------------
__global__ __launch_bounds__(512, 2) void attn_kernel(
    const bf16* __restrict__ qkv, const float* __restrict__ mask,
    bf16* __restrict__ ctx)
{
  __shared__ bf16 Kl[S_*KST];
  __shared__ bf16 Vt[DH_*VST];
  __shared__ float mk[S_];
  __shared__ bf16 Pl[8][16*PST];
  int bid = blockIdx.x;
  int half = bid & 1, bh = bid >> 1;
  int h = bh % NH_, b = bh / NH_;
  int tid = threadIdx.x, lane = tid & 63, wid = tid >> 6;
  int lrow = lane & 15, kgrp = lane >> 4;
  const bf16* Qb = qkv + (size_t)(b*S_)*QKV_        + h*DH_;
  const bf16* Kb = qkv + (size_t)(b*S_)*QKV_ + H_   + h*DH_;
  const bf16* Vb = qkv + (size_t)(b*S_)*QKV_ + 2*H_ + h*DH_;

  for (int it = 0; it < 8; ++it) {
    int slot = it*512 + tid;
    int s = slot >> 3, c8 = (slot & 7)*8;
    *(bf16x8*)&Kl[s*KST + c8] = *(const bf16x8*)&Kb[(size_t)s*QKV_ + c8];
    bf16x8 v = *(const bf16x8*)&Vb[(size_t)s*QKV_ + c8];
#pragma unroll
    for (int i = 0; i < 8; ++i) Vt[(c8+i)*VST + s] = v[i];
  }
  mk[tid] = mask[b*S_ + tid];
  __syncthreads();

  for (int pass = 0; pass < 2; ++pass) {
    int q0 = half*256 + pass*128 + wid*16;
    bf16x8 qa[2];
#pragma unroll
    for (int kc = 0; kc < 2; ++kc)
      qa[kc] = *(const bf16x8*)&Qb[(size_t)(q0 + lrow)*QKV_ + kc*32 + kgrp*8];
    f32x4 O[4] = {};
    float mrun[4], lrun[4];
#pragma unroll
    for (int r = 0; r < 4; ++r) { mrun[r] = -1e30f; lrun[r] = 0.f; }

    for (int c0 = 0; c0 < S_; c0 += 64) {
      f32x4 Sf[4] = {};
      __builtin_amdgcn_s_setprio(1);
#pragma unroll
      for (int kc = 0; kc < 2; ++kc)
#pragma unroll
        for (int sn = 0; sn < 4; ++sn) {
          bf16x8 kbv = *(const bf16x8*)&Kl[(c0 + sn*16 + lrow)*KST + kc*32 + kgrp*8];
          Sf[sn] = __builtin_amdgcn_mfma_f32_16x16x32_bf16(qa[kc], kbv, Sf[sn], 0, 0, 0);
        }
      __builtin_amdgcn_s_setprio(0);
      float cmax[4];
#pragma unroll
      for (int r = 0; r < 4; ++r) cmax[r] = -1e30f;
#pragma unroll
      for (int sn = 0; sn < 4; ++sn)
#pragma unroll
        for (int r = 0; r < 4; ++r) {
          Sf[sn][r] *= 0.125f;
          cmax[r] = fmaxf(cmax[r], Sf[sn][r]);
        }
      for (int o = 1; o < 16; o <<= 1)
#pragma unroll
        for (int r = 0; r < 4; ++r) cmax[r] = fmaxf(cmax[r], __shfl_xor(cmax[r], o));
      float newm[4], fr[4], lsum[4];
#pragma unroll
      for (int r = 0; r < 4; ++r) {
        newm[r] = fmaxf(mrun[r], cmax[r]);
        fr[r]   = __expf(mrun[r] - newm[r]);
        lsum[r] = 0.f;
      }
#pragma unroll
      for (int sn = 0; sn < 4; ++sn) {
        float mkv = mk[c0 + sn*16 + lrow];
#pragma unroll
        for (int r = 0; r < 4; ++r) {
          float e = __expf(Sf[sn][r] - newm[r]) * mkv;
          bf16 eb = (bf16)e;
          lsum[r] += (float)eb;
          Pl[wid][(kgrp*4 + r)*PST + sn*16 + lrow] = eb;
        }
      }
      for (int o = 1; o < 16; o <<= 1)
#pragma unroll
        for (int r = 0; r < 4; ++r) lsum[r] += __shfl_xor(lsum[r], o);
#pragma unroll
      for (int r = 0; r < 4; ++r) { lrun[r] = lrun[r]*fr[r] + lsum[r]; mrun[r] = newm[r]; }
#pragma unroll
      for (int on = 0; on < 4; ++on)
#pragma unroll
        for (int r = 0; r < 4; ++r) O[on][r] *= fr[r];
      asm volatile("s_waitcnt lgkmcnt(0)" ::: "memory");
      __builtin_amdgcn_sched_barrier(0);
      __builtin_amdgcn_s_setprio(1);
#pragma unroll
      for (int kc = 0; kc < 2; ++kc) {
        bf16x8 pa = *(const bf16x8*)&Pl[wid][lrow*PST + kc*32 + kgrp*8];
#pragma unroll
        for (int on = 0; on < 4; ++on) {
          bf16x8 vv = *(const bf16x8*)&Vt[(on*16 + lrow)*VST + c0 + kc*32 + kgrp*8];
          O[on] = __builtin_amdgcn_mfma_f32_16x16x32_bf16(pa, vv, O[on], 0, 0, 0);
        }
      }
      __builtin_amdgcn_s_setprio(0);
    }
#pragma unroll
    for (int on = 0; on < 4; ++on)
#pragma unroll
      for (int r = 0; r < 4; ++r) {
        float val = O[on][r] / fmaxf(lrun[r], 1e-9f);
        int q = q0 + kgrp*4 + r;
        ctx[(size_t)(b*S_ + q)*H_ + h*DH_ + on*16 + lrow] = (bf16)val;
      }
  }
}

// ---------------- masked mean pool + L2 normalize ----------------
__global__ __launch_bounds__(256) void pool_norm(
    const float* __restrict__ h32, const float* __restrict__ mask,
    float* __restrict__ out)
{
  __shared__ float red[8];
  int b = blockIdx.x, t = threadIdx.x;
  float a0 = 0.f, a1 = 0.f, a2 = 0.f;
  for (int s = 0; s < S_; ++s) {
    float m = mask[b*S_ + s];
    const float* hp = &h32[((size_t)b*S_ + s)*H_];
    a0 += hp[t]*m; a1 += hp[t+256]*m; a2 += hp[t+512]*m;
  }
  float msum = mask[b*S_ + t] + mask[b*S_ + 256 + t];
  float dummy = 0.f;
  block_sum2(msum, dummy, red);
  float inv = 1.f / fmaxf(msum, 1e-6f);
  float s0 = a0*inv, s1 = a1*inv, s2 = a2*inv;
  float nrm = s0*s0 + s1*s1 + s2*s2;
  dummy = 0.f;
  block_sum2(nrm, dummy, red);
  float rn = 1.f / fmaxf(sqrtf(nrm), 1e-12f);
  out[b*H_ + t]       = s0*rn;
  out[b*H_ + t + 256] = s1*rn;
  out[b*H_ + t + 512] = s2*rn;
}

// ---------------- host driver ----------------
extern "C" void kernel_launch(void* const* d_in, const int* in_sizes, int n_in,
                              void* d_out, int out_size, void* d_ws, size_t ws_size,
                              hipStream_t stream)
{
  const int*   ids  = (const int*)  d_in[0];
  const float* mask = (const float*)d_in[1];
  const float* we   = (const float*)d_in[2];
  const float* pe   = (const float*)d_in[3];
  const float* te   = (const float*)d_in[4];
  const float* les  = (const float*)d_in[5];
  const float* leb  = (const float*)d_in[6];
  const float* Wq   = (const float*)d_in[7];
  const float* bq   = (const float*)d_in[8];
  const float* Wk   = (const float*)d_in[9];
  const float* bk   = (const float*)d_in[10];
  const float* Wv   = (const float*)d_in[11];
  const float* bv   = (const float*)d_in[12];
  const float* Wo   = (const float*)d_in[13];
  const float* bo   = (const float*)d_in[14];
  const float* l1s  = (const float*)d_in[15];
  const float* l1b  = (const float*)d_in[16];
  const float* Wi   = (const float*)d_in[17];
  const float* bi   = (const float*)d_in[18];
  const float* Wf   = (const float*)d_in[19];
  const float* bfp  = (const float*)d_in[20];
  const float* l2s  = (const float*)d_in[21];
  const float* l2b  = (const float*)d_in[22];

  char* p = (char*)d_ws;
  auto alloc = [&](size_t bytes) { char* q = p; p += (bytes + 255) & ~(size_t)255; return q; };
  bf16*  wqkv = (bf16*) alloc((size_t)QKV_*H_*2);
  bf16*  wot  = (bf16*) alloc((size_t)H_*H_*2);
  bf16*  wit  = (bf16*) alloc((size_t)H_*FF_*2);
  bf16*  wft  = (bf16*) alloc((size_t)H_*FF_*2);
  float* qkbias=(float*)alloc((size_t)QKV_*4);
  bf16*  hb   = (bf16*) alloc((size_t)M_*H_*2);
  float* h32  = (float*)alloc((size_t)M_*H_*4);
  float* a32  = (float*)alloc((size_t)M_*H_*4);
  float* tmp  = (float*)alloc((size_t)M_*H_*4);
  bf16*  qkvb = (bf16*) alloc((size_t)M_*QKV_*2);
  bf16*  cxb  = (bf16*) alloc((size_t)M_*H_*2);
  bf16*  inb  = (bf16*) alloc((size_t)M_*FF_*2);

  embed_ln<<<M_, 256, 0, stream>>>(ids, we, pe, te, les, leb, h32, hb);

  for (int l = 0; l < L_; ++l) {
    size_t wsq = (size_t)l*H_*H_;
    transpose_w<<<dim3(H_/64,  H_/64 ), 256, 0, stream>>>(Wq + wsq, wqkv,            H_, H_);
    transpose_w<<<dim3(H_/64,  H_/64 ), 256, 0, stream>>>(Wk + wsq, wqkv + 768*768,  H_, H_);
    transpose_w<<<dim3(H_/64,  H_/64 ), 256, 0, stream>>>(Wv + wsq, wqkv + 2*768*768,H_, H_);
    transpose_w<<<dim3(H_/64,  H_/64 ), 256, 0, stream>>>(Wo + wsq, wot, H_, H_);
    transpose_w<<<dim3(H_/64,  FF_/64), 256, 0, stream>>>(Wi + (size_t)l*H_*FF_, wit, H_, FF_);
    transpose_w<<<dim3(FF_/64, H_/64 ), 256, 0, stream>>>(Wf + (size_t)l*FF_*H_, wft, FF_, H_);
    pack_qkv_bias<<<QKV_/256, 256, 0, stream>>>(bq + l*H_, bk + l*H_, bv + l*H_, qkbias);

    gemm256<<<64*(QKV_/256), 512, 0, stream>>>(hb,  wqkv, qkbias,      qkvb, QKV_, H_,  QKV_/256, 0);
    attn_kernel<<<B_*NH_*2, 512, 0, stream>>>(qkvb, mask, cxb);
    gemm256<<<64*(H_/256),  512, 0, stream>>>(cxb, wot, bo  + l*H_,  tmp,  H_,  H_,  H_/256,  1);
    ln_res<<<M_, 256, 0, stream>>>(tmp, h32, l1s + l*H_, l1b + l*H_, a32, hb);
    gemm256<<<64*(FF_/256), 512, 0, stream>>>(hb,  wit, bi  + l*FF_, inb,  FF_, H_,  FF_/256, 2);
    gemm256<<<64*(H_/256),  512, 0, stream>>>(inb, wft, bfp + l*H_,  tmp,  H_,  FF_, H_/256,  1);
    ln_res<<<M_, 256, 0, stream>>>(tmp, a32, l2s + l*H_, l2b + l*H_, h32, hb);
  }

  pool_norm<<<B_, 256, 0, stream>>>(h32, mask, (float*)d_out);
}

// Round 5
// 6217.004 us; speedup vs baseline: 1.5186x; 1.0844x over previous
//
#include <hip/hip_runtime.h>
#include <hip/hip_bf16.h>
#include <math.h>

typedef __bf16 bf16;
typedef __bf16 bf16x8 __attribute__((ext_vector_type(8)));
typedef float  f32x4  __attribute__((ext_vector_type(4)));

#define B_  32
#define S_  512
#define H_  768
#define NH_ 12
#define DH_ 64
#define FF_ 3072
#define L_  12
#define M_  (B_*S_)
#define QKV_ 2304   // packed q|k|v row stride

// padded LDS strides (attention bank-conflict fix)
#define KST 68
#define VST 516
#define PST 68

// ---- async global->LDS, 16B per lane; lds base must be wave-uniform ----
__device__ __forceinline__ void gload16(const bf16* g, bf16* l) {
  __builtin_amdgcn_global_load_lds(
      (const __attribute__((address_space(1))) void*)g,
      (__attribute__((address_space(3))) void*)l, 16, 0, 0);
}

// =================== 128x128 m97-structure GEMM ===================
// C[M,N] = A[M,K] * Bt[N,K]^T + bias.  epi: 0 bf16, 1 f32, 2 gelu->bf16
// Single-buffered 32KB LDS -> 2-3 blocks/CU; overlap comes from co-resident
// blocks (m114 wave-level overlap), not intra-block pipelining (m97: 912 TF).
// XOR swizzle (slot ^= row&7) on staging source + ds_read: 0 bank conflicts.
__global__ __launch_bounds__(256) void gemm128(
    const bf16* __restrict__ A, const bf16* __restrict__ Bt,
    const float* __restrict__ bias, void* __restrict__ outp,
    int N, int K, int tiles_n, int epi)
{
  __shared__ bf16 As[128*64];   // 16 KB
  __shared__ bf16 Bs[128*64];   // 16 KB
  const int tid  = threadIdx.x;
  const int lane = tid & 63, wid = tid >> 6;
  const int wr = wid >> 1, wc = wid & 1;          // 2 x 2 wave grid
  const int lrow = lane & 15, kgrp = lane >> 4;

  // bijective XCD swizzle (m204)
  const int nwg = gridDim.x, orig = blockIdx.x;
  const int qc = nwg >> 3, rc = nwg & 7;
  const int xcd = orig & 7, lin = orig >> 3;
  const int wg = (xcd < rc ? xcd*(qc+1) : rc*(qc+1) + (xcd-rc)*qc) + lin;
  const int tm = wg / tiles_n, tn = wg % tiles_n;
  const size_t m0 = (size_t)tm * 128, n0 = (size_t)tn * 128;
  const int KT = K >> 6;

  const bf16* Ab = A  + m0 * K;
  const bf16* Bb = Bt + n0 * K;

  // stage a full 128x64 tile (16 KB): 4 gload16/thread, source pre-swizzled
  auto stage = [&](const bf16* gbase, bf16* ldsbase, int kt) {
#pragma unroll
    for (int j = 0; j < 4; ++j) {
      int lin2  = j*256 + tid;
      int prow  = lin2 >> 3;             // 0..127
      int pslot = lin2 & 7;              // physical 16B slot
      int lslot = pslot ^ (prow & 7);    // logical slot (involution)
      const bf16* src = gbase + (size_t)prow * K + (size_t)kt*64 + lslot*8;
      bf16* dst = ldsbase + (size_t)(j*256 + (wid<<6))*8;  // wave-uniform base
      gload16(src, dst);
    }
  };

  f32x4 acc[4][4] = {};

  for (int t = 0; t < KT; ++t) {
    __syncthreads();                      // prev iteration's ds_reads done
    stage(Ab, As, t);
    stage(Bb, Bs, t);
    __syncthreads();                      // drains vmcnt(0) -> tiles visible
#pragma unroll
    for (int kk = 0; kk < 2; ++kk) {
      bf16x8 a[4], b[4];
#pragma unroll
      for (int m = 0; m < 4; ++m) {
        int row  = wr*64 + m*16 + lrow;
        int slot = (kk*4 + kgrp) ^ (lrow & 7);
        a[m] = *(const bf16x8*)&As[row*64 + slot*8];
      }
#pragma unroll
      for (int n = 0; n < 4; ++n) {
        int row  = wc*64 + n*16 + lrow;
        int slot = (kk*4 + kgrp) ^ (lrow & 7);
        b[n] = *(const bf16x8*)&Bs[row*64 + slot*8];
      }
#pragma unroll
      for (int m = 0; m < 4; ++m)
#pragma unroll
        for (int n = 0; n < 4; ++n)
          acc[m][n] = __builtin_amdgcn_mfma_f32_16x16x32_bf16(a[m], b[n], acc[m][n], 0, 0, 0);
    }
  }

  // epilogue: row = m0+wr*64+m*16+kgrp*4+r, col = n0+wc*64+n*16+lrow (verified r1)
#pragma unroll
  for (int m = 0; m < 4; ++m)
#pragma unroll
    for (int n = 0; n < 4; ++n) {
      int col = (int)n0 + wc*64 + n*16 + lrow;
      float bv = bias[col];
#pragma unroll
      for (int r = 0; r < 4; ++r) {
        int row = (int)m0 + wr*64 + m*16 + kgrp*4 + r;
        float x = acc[m][n][r] + bv;
        size_t idx = (size_t)row * N + col;
        if (epi == 1)      ((float*)outp)[idx] = x;
        else if (epi == 0) ((bf16*)outp)[idx]  = (bf16)x;
        else               ((bf16*)outp)[idx]  = (bf16)(0.5f * x * (1.0f + erff(x * 0.70710678118f)));
      }
    }
}

// ---------------- weight transpose + fp32->bf16 ----------------
__global__ __launch_bounds__(256) void transpose_w(
    const float* __restrict__ W, bf16* __restrict__ Wt, int K, int N)
{
  __shared__ bf16 T[64][65];
  int k0 = blockIdx.x * 64, n0 = blockIdx.y * 64;
  int tx = threadIdx.x & 63, ty = threadIdx.x >> 6;
#pragma unroll
  for (int j = 0; j < 16; ++j) {
    int kk = j*4 + ty;
    T[kk][tx] = (bf16)W[(size_t)(k0+kk)*N + n0 + tx];
  }
  __syncthreads();
#pragma unroll
  for (int j = 0; j < 16; ++j) {
    int nn = j*4 + ty;
    Wt[(size_t)(n0+nn)*K + k0 + tx] = T[tx][nn];
  }
}

__global__ __launch_bounds__(256) void pack_qkv_bias(
    const float* __restrict__ bq, const float* __restrict__ bk,
    const float* __restrict__ bv, float* __restrict__ out)
{
  int i = blockIdx.x*256 + threadIdx.x;
  out[i] = (i < 768) ? bq[i] : (i < 1536 ? bk[i-768] : bv[i-1536]);
}

// ---------------- block reductions ----------------
__device__ __forceinline__ void block_sum2(float& a, float& b, float* red) {
  int lane = threadIdx.x & 63, wid = threadIdx.x >> 6;
  for (int o = 32; o > 0; o >>= 1) { a += __shfl_xor(a, o); b += __shfl_xor(b, o); }
  if (lane == 0) { red[wid*2] = a; red[wid*2+1] = b; }
  __syncthreads();
  a = red[0] + red[2] + red[4] + red[6];
  b = red[1] + red[3] + red[5] + red[7];
  __syncthreads();
}

// ---------------- embedding + LN ----------------
__global__ __launch_bounds__(256) void embed_ln(
    const int* __restrict__ ids, const float* __restrict__ we,
    const float* __restrict__ pe, const float* __restrict__ te,
    const float* __restrict__ gs, const float* __restrict__ gb,
    float* __restrict__ h32, bf16* __restrict__ hb)
{
  __shared__ float red[8];
  int row = blockIdx.x;
  int s = row & (S_-1);
  int id = ids[row];
  int t = threadIdx.x;
  float x[3], sum = 0.f, sq = 0.f;
#pragma unroll
  for (int j = 0; j < 3; ++j) {
    int c = t + j*256;
    float v = we[(size_t)id*H_ + c] + pe[(size_t)s*H_ + c] + te[c];
    x[j] = v; sum += v; sq += v*v;
  }
  block_sum2(sum, sq, red);
  float mean = sum * (1.f/H_);
  float var  = sq  * (1.f/H_) - mean*mean;
  float rstd = rsqrtf(fmaxf(var, 0.f) + 1e-12f);
#pragma unroll
  for (int j = 0; j < 3; ++j) {
    int c = t + j*256;
    float y = (x[j]-mean)*rstd*gs[c] + gb[c];
    h32[(size_t)row*H_ + c] = y;
    hb [(size_t)row*H_ + c] = (bf16)y;
  }
}

// ---------------- residual add + LN ----------------
__global__ __launch_bounds__(256) void ln_res(
    const float* __restrict__ t32, const float* __restrict__ res,
    const float* __restrict__ gs, const float* __restrict__ gb,
    float* __restrict__ o32, bf16* __restrict__ ob)
{
  __shared__ float red[8];
  int row = blockIdx.x, t = threadIdx.x;
  float x[3], sum = 0.f, sq = 0.f;
#pragma unroll
  for (int j = 0; j < 3; ++j) {
    int c = t + j*256;
    float v = t32[(size_t)row*H_ + c] + res[(size_t)row*H_ + c];
    x[j] = v; sum += v; sq += v*v;
  }
  block_sum2(sum, sq, red);
  float mean = sum * (1.f/H_);
  float var  = sq  * (1.f/H_) - mean*mean;
  float rstd = rsqrtf(fmaxf(var, 0.f) + 1e-12f);
#pragma unroll
  for (int j = 0; j < 3; ++j) {
    int c = t + j*256;
    float y = (x[j]-mean)*rstd*gs[c] + gb[c];
    o32[(size_t)row*H_ + c] = y;
    ob [(size_t)row*H_ + c] = (bf16)y;
  }
}

// ---------------- fused attention: 512 threads, padded LDS ----------------
__global__ __launch_bounds__(512, 2) void attn_kernel(
    const bf16* __restrict__ qkv, const float* __restrict__ mask,
    bf16* __restrict__ ctx)
{
  __shared__ bf16 Kl[S_*KST];
  __shared__ bf16 Vt[DH_*VST];
  __shared__ float mk[S_];
  __shared__ bf16 Pl[8][16*PST];
  int bid = blockIdx.x;
  int half = bid & 1, bh = bid >> 1;
  int h = bh % NH_, b = bh / NH_;
  int tid = threadIdx.x, lane = tid & 63, wid = tid >> 6;
  int lrow = lane & 15, kgrp = lane >> 4;
  const bf16* Qb = qkv + (size_t)(b*S_)*QKV_        + h*DH_;
  const bf16* Kb = qkv + (size_t)(b*S_)*QKV_ + H_   + h*DH_;
  const bf16* Vb = qkv + (size_t)(b*S_)*QKV_ + 2*H_ + h*DH_;

  for (int it = 0; it < 8; ++it) {
    int slot = it*512 + tid;
    int s = slot >> 3, c8 = (slot & 7)*8;
    *(bf16x8*)&Kl[s*KST + c8] = *(const bf16x8*)&Kb[(size_t)s*QKV_ + c8];
    bf16x8 v = *(const bf16x8*)&Vb[(size_t)s*QKV_ + c8];
#pragma unroll
    for (int i = 0; i < 8; ++i) Vt[(c8+i)*VST + s] = v[i];
  }
  mk[tid] = mask[b*S_ + tid];
  __syncthreads();

  for (int pass = 0; pass < 2; ++pass) {
    int q0 = half*256 + pass*128 + wid*16;
    bf16x8 qa[2];
#pragma unroll
    for (int kc = 0; kc < 2; ++kc)
      qa[kc] = *(const bf16x8*)&Qb[(size_t)(q0 + lrow)*QKV_ + kc*32 + kgrp*8];
    f32x4 O[4] = {};
    float mrun[4], lrun[4];
#pragma unroll
    for (int r = 0; r < 4; ++r) { mrun[r] = -1e30f; lrun[r] = 0.f; }

    for (int c0 = 0; c0 < S_; c0 += 64) {
      f32x4 Sf[4] = {};
      __builtin_amdgcn_s_setprio(1);
#pragma unroll
      for (int kc = 0; kc < 2; ++kc)
#pragma unroll
        for (int sn = 0; sn < 4; ++sn) {
          bf16x8 kbv = *(const bf16x8*)&Kl[(c0 + sn*16 + lrow)*KST + kc*32 + kgrp*8];
          Sf[sn] = __builtin_amdgcn_mfma_f32_16x16x32_bf16(qa[kc], kbv, Sf[sn], 0, 0, 0);
        }
      __builtin_amdgcn_s_setprio(0);
      float cmax[4];
#pragma unroll
      for (int r = 0; r < 4; ++r) cmax[r] = -1e30f;
#pragma unroll
      for (int sn = 0; sn < 4; ++sn)
#pragma unroll
        for (int r = 0; r < 4; ++r) {
          Sf[sn][r] *= 0.125f;
          cmax[r] = fmaxf(cmax[r], Sf[sn][r]);
        }
      for (int o = 1; o < 16; o <<= 1)
#pragma unroll
        for (int r = 0; r < 4; ++r) cmax[r] = fmaxf(cmax[r], __shfl_xor(cmax[r], o));
      float newm[4], fr[4], lsum[4];
#pragma unroll
      for (int r = 0; r < 4; ++r) {
        newm[r] = fmaxf(mrun[r], cmax[r]);
        fr[r]   = __expf(mrun[r] - newm[r]);
        lsum[r] = 0.f;
      }
#pragma unroll
      for (int sn = 0; sn < 4; ++sn) {
        float mkv = mk[c0 + sn*16 + lrow];
#pragma unroll
        for (int r = 0; r < 4; ++r) {
          float e = __expf(Sf[sn][r] - newm[r]) * mkv;
          bf16 eb = (bf16)e;
          lsum[r] += (float)eb;
          Pl[wid][(kgrp*4 + r)*PST + sn*16 + lrow] = eb;
        }
      }
      for (int o = 1; o < 16; o <<= 1)
#pragma unroll
        for (int r = 0; r < 4; ++r) lsum[r] += __shfl_xor(lsum[r], o);
#pragma unroll
      for (int r = 0; r < 4; ++r) { lrun[r] = lrun[r]*fr[r] + lsum[r]; mrun[r] = newm[r]; }
#pragma unroll
      for (int on = 0; on < 4; ++on)
#pragma unroll
        for (int r = 0; r < 4; ++r) O[on][r] *= fr[r];
      asm volatile("s_waitcnt lgkmcnt(0)" ::: "memory");
      __builtin_amdgcn_sched_barrier(0);
      __builtin_amdgcn_s_setprio(1);
#pragma unroll
      for (int kc = 0; kc < 2; ++kc) {
        bf16x8 pa = *(const bf16x8*)&Pl[wid][lrow*PST + kc*32 + kgrp*8];
#pragma unroll
        for (int on = 0; on < 4; ++on) {
          bf16x8 vv = *(const bf16x8*)&Vt[(on*16 + lrow)*VST + c0 + kc*32 + kgrp*8];
          O[on] = __builtin_amdgcn_mfma_f32_16x16x32_bf16(pa, vv, O[on], 0, 0, 0);
        }
      }
      __builtin_amdgcn_s_setprio(0);
    }
#pragma unroll
    for (int on = 0; on < 4; ++on)
#pragma unroll
      for (int r = 0; r < 4; ++r) {
        float val = O[on][r] / fmaxf(lrun[r], 1e-9f);
        int q = q0 + kgrp*4 + r;
        ctx[(size_t)(b*S_ + q)*H_ + h*DH_ + on*16 + lrow] = (bf16)val;
      }
  }
}

// ---------------- masked mean pool + L2 normalize ----------------
__global__ __launch_bounds__(256) void pool_norm(
    const float* __restrict__ h32, const float* __restrict__ mask,
    float* __restrict__ out)
{
  __shared__ float red[8];
  int b = blockIdx.x, t = threadIdx.x;
  float a0 = 0.f, a1 = 0.f, a2 = 0.f;
  for (int s = 0; s < S_; ++s) {
    float m = mask[b*S_ + s];
    const float* hp = &h32[((size_t)b*S_ + s)*H_];
    a0 += hp[t]*m; a1 += hp[t+256]*m; a2 += hp[t+512]*m;
  }
  float msum = mask[b*S_ + t] + mask[b*S_ + 256 + t];
  float dummy = 0.f;
  block_sum2(msum, dummy, red);
  float inv = 1.f / fmaxf(msum, 1e-6f);
  float s0 = a0*inv, s1 = a1*inv, s2 = a2*inv;
  float nrm = s0*s0 + s1*s1 + s2*s2;
  dummy = 0.f;
  block_sum2(nrm, dummy, red);
  float rn = 1.f / fmaxf(sqrtf(nrm), 1e-12f);
  out[b*H_ + t]       = s0*rn;
  out[b*H_ + t + 256] = s1*rn;
  out[b*H_ + t + 512] = s2*rn;
}

// ---------------- host driver ----------------
extern "C" void kernel_launch(void* const* d_in, const int* in_sizes, int n_in,
                              void* d_out, int out_size, void* d_ws, size_t ws_size,
                              hipStream_t stream)
{
  const int*   ids  = (const int*)  d_in[0];
  const float* mask = (const float*)d_in[1];
  const float* we   = (const float*)d_in[2];
  const float* pe   = (const float*)d_in[3];
  const float* te   = (const float*)d_in[4];
  const float* les  = (const float*)d_in[5];
  const float* leb  = (const float*)d_in[6];
  const float* Wq   = (const float*)d_in[7];
  const float* bq   = (const float*)d_in[8];
  const float* Wk   = (const float*)d_in[9];
  const float* bk   = (const float*)d_in[10];
  const float* Wv   = (const float*)d_in[11];
  const float* bv   = (const float*)d_in[12];
  const float* Wo   = (const float*)d_in[13];
  const float* bo   = (const float*)d_in[14];
  const float* l1s  = (const float*)d_in[15];
  const float* l1b  = (const float*)d_in[16];
  const float* Wi   = (const float*)d_in[17];
  const float* bi   = (const float*)d_in[18];
  const float* Wf   = (const float*)d_in[19];
  const float* bfp  = (const float*)d_in[20];
  const float* l2s  = (const float*)d_in[21];
  const float* l2b  = (const float*)d_in[22];

  char* p = (char*)d_ws;
  auto alloc = [&](size_t bytes) { char* q = p; p += (bytes + 255) & ~(size_t)255; return q; };
  bf16*  wqkv = (bf16*) alloc((size_t)QKV_*H_*2);
  bf16*  wot  = (bf16*) alloc((size_t)H_*H_*2);
  bf16*  wit  = (bf16*) alloc((size_t)H_*FF_*2);
  bf16*  wft  = (bf16*) alloc((size_t)H_*FF_*2);
  float* qkbias=(float*)alloc((size_t)QKV_*4);
  bf16*  hb   = (bf16*) alloc((size_t)M_*H_*2);
  float* h32  = (float*)alloc((size_t)M_*H_*4);
  float* a32  = (float*)alloc((size_t)M_*H_*4);
  float* tmp  = (float*)alloc((size_t)M_*H_*4);
  bf16*  qkvb = (bf16*) alloc((size_t)M_*QKV_*2);
  bf16*  cxb  = (bf16*) alloc((size_t)M_*H_*2);
  bf16*  inb  = (bf16*) alloc((size_t)M_*FF_*2);

  embed_ln<<<M_, 256, 0, stream>>>(ids, we, pe, te, les, leb, h32, hb);

  for (int l = 0; l < L_; ++l) {
    size_t wsq = (size_t)l*H_*H_;
    transpose_w<<<dim3(H_/64,  H_/64 ), 256, 0, stream>>>(Wq + wsq, wqkv,            H_, H_);
    transpose_w<<<dim3(H_/64,  H_/64 ), 256, 0, stream>>>(Wk + wsq, wqkv + 768*768,  H_, H_);
    transpose_w<<<dim3(H_/64,  H_/64 ), 256, 0, stream>>>(Wv + wsq, wqkv + 2*768*768,H_, H_);
    transpose_w<<<dim3(H_/64,  H_/64 ), 256, 0, stream>>>(Wo + wsq, wot, H_, H_);
    transpose_w<<<dim3(H_/64,  FF_/64), 256, 0, stream>>>(Wi + (size_t)l*H_*FF_, wit, H_, FF_);
    transpose_w<<<dim3(FF_/64, H_/64 ), 256, 0, stream>>>(Wf + (size_t)l*FF_*H_, wft, FF_, H_);
    pack_qkv_bias<<<QKV_/256, 256, 0, stream>>>(bq + l*H_, bk + l*H_, bv + l*H_, qkbias);

    gemm128<<<128*(QKV_/128), 256, 0, stream>>>(hb,  wqkv, qkbias,      qkvb, QKV_, H_,  QKV_/128, 0);
    attn_kernel<<<B_*NH_*2, 512, 0, stream>>>(qkvb, mask, cxb);
    gemm128<<<128*(H_/128),  256, 0, stream>>>(cxb, wot, bo  + l*H_,  tmp,  H_,  H_,  H_/128,  1);
    ln_res<<<M_, 256, 0, stream>>>(tmp, h32, l1s + l*H_, l1b + l*H_, a32, hb);
    gemm128<<<128*(FF_/128), 256, 0, stream>>>(hb,  wit, bi  + l*FF_, inb,  FF_, H_,  FF_/128, 2);
    gemm128<<<128*(H_/128),  256, 0, stream>>>(inb, wft, bfp + l*H_,  tmp,  H_,  FF_, H_/128,  1);
    ln_res<<<M_, 256, 0, stream>>>(tmp, a32, l2s + l*H_, l2b + l*H_, h32, hb);
  }

  pool_norm<<<B_, 256, 0, stream>>>(h32, mask, (float*)d_out);
}

// Round 6
// 6071.369 us; speedup vs baseline: 1.5550x; 1.0240x over previous
//
#include <hip/hip_runtime.h>
#include <hip/hip_bf16.h>
#include <math.h>

typedef __bf16 bf16;
typedef __bf16 bf16x8 __attribute__((ext_vector_type(8)));
typedef float  f32x4  __attribute__((ext_vector_type(4)));

#define B_  32
#define S_  512
#define H_  768
#define NH_ 12
#define DH_ 64
#define FF_ 3072
#define L_  12
#define M_  (B_*S_)
#define QKV_ 2304   // packed q|k|v row stride

// padded LDS strides (attention bank-conflict fix)
#define KST 68
#define VST 516
#define PST 68

// ---- async global->LDS, 16B per lane; lds base must be wave-uniform ----
__device__ __forceinline__ void gload16(const bf16* g, bf16* l) {
  __builtin_amdgcn_global_load_lds(
      (const __attribute__((address_space(1))) void*)g,
      (__attribute__((address_space(3))) void*)l, 16, 0, 0);
}

// ---- fast exact-GELU: Abramowitz-Stegun 7.1.26 erf, |err| < 1.5e-7 ----
// ~14 VALU insts vs ~100 for OCML erff (r5: GELU epilogue was 80% of FFN1 VALU)
__device__ __forceinline__ float fast_gelu(float x) {
  float z = x * 0.70710678118f;
  float s = fabsf(z);
  float t = __builtin_amdgcn_rcpf(1.0f + 0.3275911f * s);
  float p = t*(0.254829592f + t*(-0.284496736f + t*(1.421413741f +
            t*(-1.453152027f + t*1.061405429f))));
  float e = p * __expf(-s*s);          // = 1 - erf(s)
  float erfv = copysignf(1.0f - e, z);
  return 0.5f * x * (1.0f + erfv);
}

// =================== 128x128 m97-structure GEMM ===================
// C[M,N] = A[M,K] * Bt[N,K]^T + bias.  epi: 0 bf16, 1 f32, 2 gelu->bf16
// Single-buffered 32KB LDS -> 2-3 blocks/CU; overlap comes from co-resident
// blocks (m114 wave-level overlap), not intra-block pipelining (m97: 912 TF).
// XOR swizzle (slot ^= row&7) on staging source + ds_read: 0 bank conflicts.
__global__ __launch_bounds__(256) void gemm128(
    const bf16* __restrict__ A, const bf16* __restrict__ Bt,
    const float* __restrict__ bias, void* __restrict__ outp,
    int N, int K, int tiles_n, int epi)
{
  __shared__ bf16 As[128*64];   // 16 KB
  __shared__ bf16 Bs[128*64];   // 16 KB
  const int tid  = threadIdx.x;
  const int lane = tid & 63, wid = tid >> 6;
  const int wr = wid >> 1, wc = wid & 1;          // 2 x 2 wave grid
  const int lrow = lane & 15, kgrp = lane >> 4;

  // bijective XCD swizzle (m204)
  const int nwg = gridDim.x, orig = blockIdx.x;
  const int qc = nwg >> 3, rc = nwg & 7;
  const int xcd = orig & 7, lin = orig >> 3;
  const int wg = (xcd < rc ? xcd*(qc+1) : rc*(qc+1) + (xcd-rc)*qc) + lin;
  const int tm = wg / tiles_n, tn = wg % tiles_n;
  const size_t m0 = (size_t)tm * 128, n0 = (size_t)tn * 128;
  const int KT = K >> 6;

  const bf16* Ab = A  + m0 * K;
  const bf16* Bb = Bt + n0 * K;

  // stage a full 128x64 tile (16 KB): 4 gload16/thread, source pre-swizzled
  auto stage = [&](const bf16* gbase, bf16* ldsbase, int kt) {
#pragma unroll
    for (int j = 0; j < 4; ++j) {
      int lin2  = j*256 + tid;
      int prow  = lin2 >> 3;             // 0..127
      int pslot = lin2 & 7;              // physical 16B slot
      int lslot = pslot ^ (prow & 7);    // logical slot (involution)
      const bf16* src = gbase + (size_t)prow * K + (size_t)kt*64 + lslot*8;
      bf16* dst = ldsbase + (size_t)(j*256 + (wid<<6))*8;  // wave-uniform base
      gload16(src, dst);
    }
  };

  f32x4 acc[4][4] = {};

  for (int t = 0; t < KT; ++t) {
    __syncthreads();                      // prev iteration's ds_reads done
    stage(Ab, As, t);
    stage(Bb, Bs, t);
    __syncthreads();                      // drains vmcnt(0) -> tiles visible
#pragma unroll
    for (int kk = 0; kk < 2; ++kk) {
      bf16x8 a[4], b[4];
#pragma unroll
      for (int m = 0; m < 4; ++m) {
        int row  = wr*64 + m*16 + lrow;
        int slot = (kk*4 + kgrp) ^ (lrow & 7);
        a[m] = *(const bf16x8*)&As[row*64 + slot*8];
      }
#pragma unroll
      for (int n = 0; n < 4; ++n) {
        int row  = wc*64 + n*16 + lrow;
        int slot = (kk*4 + kgrp) ^ (lrow & 7);
        b[n] = *(const bf16x8*)&Bs[row*64 + slot*8];
      }
#pragma unroll
      for (int m = 0; m < 4; ++m)
#pragma unroll
        for (int n = 0; n < 4; ++n)
          acc[m][n] = __builtin_amdgcn_mfma_f32_16x16x32_bf16(a[m], b[n], acc[m][n], 0, 0, 0);
    }
  }

  // epilogue: row = m0+wr*64+m*16+kgrp*4+r, col = n0+wc*64+n*16+lrow (verified r1)
#pragma unroll
  for (int m = 0; m < 4; ++m)
#pragma unroll
    for (int n = 0; n < 4; ++n) {
      int col = (int)n0 + wc*64 + n*16 + lrow;
      float bv = bias[col];
#pragma unroll
      for (int r = 0; r < 4; ++r) {
        int row = (int)m0 + wr*64 + m*16 + kgrp*4 + r;
        float x = acc[m][n][r] + bv;
        size_t idx = (size_t)row * N + col;
        if (epi == 1)      ((float*)outp)[idx] = x;
        else if (epi == 0) ((bf16*)outp)[idx]  = (bf16)x;
        else               ((bf16*)outp)[idx]  = (bf16)fast_gelu(x);
      }
    }
}

// ---------------- weight transpose + fp32->bf16 ----------------
__global__ __launch_bounds__(256) void transpose_w(
    const float* __restrict__ W, bf16* __restrict__ Wt, int K, int N)
{
  __shared__ bf16 T[64][65];
  int k0 = blockIdx.x * 64, n0 = blockIdx.y * 64;
  int tx = threadIdx.x & 63, ty = threadIdx.x >> 6;
#pragma unroll
  for (int j = 0; j < 16; ++j) {
    int kk = j*4 + ty;
    T[kk][tx] = (bf16)W[(size_t)(k0+kk)*N + n0 + tx];
  }
  __syncthreads();
#pragma unroll
  for (int j = 0; j < 16; ++j) {
    int nn = j*4 + ty;
    Wt[(size_t)(n0+nn)*K + k0 + tx] = T[tx][nn];
  }
}

__global__ __launch_bounds__(256) void pack_qkv_bias(
    const float* __restrict__ bq, const float* __restrict__ bk,
    const float* __restrict__ bv, float* __restrict__ out)
{
  int i = blockIdx.x*256 + threadIdx.x;
  out[i] = (i < 768) ? bq[i] : (i < 1536 ? bk[i-768] : bv[i-1536]);
}

// ---------------- block reductions ----------------
__device__ __forceinline__ void block_sum2(float& a, float& b, float* red) {
  int lane = threadIdx.x & 63, wid = threadIdx.x >> 6;
  for (int o = 32; o > 0; o >>= 1) { a += __shfl_xor(a, o); b += __shfl_xor(b, o); }
  if (lane == 0) { red[wid*2] = a; red[wid*2+1] = b; }
  __syncthreads();
  a = red[0] + red[2] + red[4] + red[6];
  b = red[1] + red[3] + red[5] + red[7];
  __syncthreads();
}

// ---------------- embedding + LN ----------------
__global__ __launch_bounds__(256) void embed_ln(
    const int* __restrict__ ids, const float* __restrict__ we,
    const float* __restrict__ pe, const float* __restrict__ te,
    const float* __restrict__ gs, const float* __restrict__ gb,
    float* __restrict__ h32, bf16* __restrict__ hb)
{
  __shared__ float red[8];
  int row = blockIdx.x;
  int s = row & (S_-1);
  int id = ids[row];
  int t = threadIdx.x;
  float x[3], sum = 0.f, sq = 0.f;
#pragma unroll
  for (int j = 0; j < 3; ++j) {
    int c = t + j*256;
    float v = we[(size_t)id*H_ + c] + pe[(size_t)s*H_ + c] + te[c];
    x[j] = v; sum += v; sq += v*v;
  }
  block_sum2(sum, sq, red);
  float mean = sum * (1.f/H_);
  float var  = sq  * (1.f/H_) - mean*mean;
  float rstd = rsqrtf(fmaxf(var, 0.f) + 1e-12f);
#pragma unroll
  for (int j = 0; j < 3; ++j) {
    int c = t + j*256;
    float y = (x[j]-mean)*rstd*gs[c] + gb[c];
    h32[(size_t)row*H_ + c] = y;
    hb [(size_t)row*H_ + c] = (bf16)y;
  }
}

// ---------------- residual add + LN ----------------
__global__ __launch_bounds__(256) void ln_res(
    const float* __restrict__ t32, const float* __restrict__ res,
    const float* __restrict__ gs, const float* __restrict__ gb,
    float* __restrict__ o32, bf16* __restrict__ ob)
{
  __shared__ float red[8];
  int row = blockIdx.x, t = threadIdx.x;
  float x[3], sum = 0.f, sq = 0.f;
#pragma unroll
  for (int j = 0; j < 3; ++j) {
    int c = t + j*256;
    float v = t32[(size_t)row*H_ + c] + res[(size_t)row*H_ + c];
    x[j] = v; sum += v; sq += v*v;
  }
  block_sum2(sum, sq, red);
  float mean = sum * (1.f/H_);
  float var  = sq  * (1.f/H_) - mean*mean;
  float rstd = rsqrtf(fmaxf(var, 0.f) + 1e-12f);
#pragma unroll
  for (int j = 0; j < 3; ++j) {
    int c = t + j*256;
    float y = (x[j]-mean)*rstd*gs[c] + gb[c];
    o32[(size_t)row*H_ + c] = y;
    ob [(size_t)row*H_ + c] = (bf16)y;
  }
}

// ---------------- fused attention: 512 threads, padded LDS ----------------
__global__ __launch_bounds__(512, 2) void attn_kernel(
    const bf16* __restrict__ qkv, const float* __restrict__ mask,
    bf16* __restrict__ ctx)
{
  __shared__ bf16 Kl[S_*KST];
  __shared__ bf16 Vt[DH_*VST];
  __shared__ float mk[S_];
  __shared__ bf16 Pl[8][16*PST];
  int bid = blockIdx.x;
  int half = bid & 1, bh = bid >> 1;
  int h = bh % NH_, b = bh / NH_;
  int tid = threadIdx.x, lane = tid & 63, wid = tid >> 6;
  int lrow = lane & 15, kgrp = lane >> 4;
  const bf16* Qb = qkv + (size_t)(b*S_)*QKV_        + h*DH_;
  const bf16* Kb = qkv + (size_t)(b*S_)*QKV_ + H_   + h*DH_;
  const bf16* Vb = qkv + (size_t)(b*S_)*QKV_ + 2*H_ + h*DH_;

  for (int it = 0; it < 8; ++it) {
    int slot = it*512 + tid;
    int s = slot >> 3, c8 = (slot & 7)*8;
    *(bf16x8*)&Kl[s*KST + c8] = *(const bf16x8*)&Kb[(size_t)s*QKV_ + c8];
    bf16x8 v = *(const bf16x8*)&Vb[(size_t)s*QKV_ + c8];
#pragma unroll
    for (int i = 0; i < 8; ++i) Vt[(c8+i)*VST + s] = v[i];
  }
  mk[tid] = mask[b*S_ + tid];
  __syncthreads();

  for (int pass = 0; pass < 2; ++pass) {
    int q0 = half*256 + pass*128 + wid*16;
    bf16x8 qa[2];
#pragma unroll
    for (int kc = 0; kc < 2; ++kc)
      qa[kc] = *(const bf16x8*)&Qb[(size_t)(q0 + lrow)*QKV_ + kc*32 + kgrp*8];
    f32x4 O[4] = {};
    float mrun[4], lrun[4];
#pragma unroll
    for (int r = 0; r < 4; ++r) { mrun[r] = -1e30f; lrun[r] = 0.f; }

    for (int c0 = 0; c0 < S_; c0 += 64) {
      f32x4 Sf[4] = {};
      __builtin_amdgcn_s_setprio(1);
#pragma unroll
      for (int kc = 0; kc < 2; ++kc)
#pragma unroll
        for (int sn = 0; sn < 4; ++sn) {
          bf16x8 kbv = *(const bf16x8*)&Kl[(c0 + sn*16 + lrow)*KST + kc*32 + kgrp*8];
          Sf[sn] = __builtin_amdgcn_mfma_f32_16x16x32_bf16(qa[kc], kbv, Sf[sn], 0, 0, 0);
        }
      __builtin_amdgcn_s_setprio(0);
      float cmax[4];
#pragma unroll
      for (int r = 0; r < 4; ++r) cmax[r] = -1e30f;
#pragma unroll
      for (int sn = 0; sn < 4; ++sn)
#pragma unroll
        for (int r = 0; r < 4; ++r) {
          Sf[sn][r] *= 0.125f;
          cmax[r] = fmaxf(cmax[r], Sf[sn][r]);
        }
      for (int o = 1; o < 16; o <<= 1)
#pragma unroll
        for (int r = 0; r < 4; ++r) cmax[r] = fmaxf(cmax[r], __shfl_xor(cmax[r], o));
      float newm[4], fr[4], lsum[4];
#pragma unroll
      for (int r = 0; r < 4; ++r) {
        newm[r] = fmaxf(mrun[r], cmax[r]);
        fr[r]   = __expf(mrun[r] - newm[r]);
        lsum[r] = 0.f;
      }
#pragma unroll
      for (int sn = 0; sn < 4; ++sn) {
        float mkv = mk[c0 + sn*16 + lrow];
#pragma unroll
        for (int r = 0; r < 4; ++r) {
          float e = __expf(Sf[sn][r] - newm[r]) * mkv;
          bf16 eb = (bf16)e;
          lsum[r] += (float)eb;
          Pl[wid][(kgrp*4 + r)*PST + sn*16 + lrow] = eb;
        }
      }
      for (int o = 1; o < 16; o <<= 1)
#pragma unroll
        for (int r = 0; r < 4; ++r) lsum[r] += __shfl_xor(lsum[r], o);
#pragma unroll
      for (int r = 0; r < 4; ++r) { lrun[r] = lrun[r]*fr[r] + lsum[r]; mrun[r] = newm[r]; }
#pragma unroll
      for (int on = 0; on < 4; ++on)
#pragma unroll
        for (int r = 0; r < 4; ++r) O[on][r] *= fr[r];
      asm volatile("s_waitcnt lgkmcnt(0)" ::: "memory");
      __builtin_amdgcn_sched_barrier(0);
      __builtin_amdgcn_s_setprio(1);
#pragma unroll
      for (int kc = 0; kc < 2; ++kc) {
        bf16x8 pa = *(const bf16x8*)&Pl[wid][lrow*PST + kc*32 + kgrp*8];
#pragma unroll
        for (int on = 0; on < 4; ++on) {
          bf16x8 vv = *(const bf16x8*)&Vt[(on*16 + lrow)*VST + c0 + kc*32 + kgrp*8];
          O[on] = __builtin_amdgcn_mfma_f32_16x16x32_bf16(pa, vv, O[on], 0, 0, 0);
        }
      }
      __builtin_amdgcn_s_setprio(0);
    }
#pragma unroll
    for (int on = 0; on < 4; ++on)
#pragma unroll
      for (int r = 0; r < 4; ++r) {
        float val = O[on][r] / fmaxf(lrun[r], 1e-9f);
        int q = q0 + kgrp*4 + r;
        ctx[(size_t)(b*S_ + q)*H_ + h*DH_ + on*16 + lrow] = (bf16)val;
      }
  }
}

// ---------------- masked mean pool + L2 normalize ----------------
__global__ __launch_bounds__(256) void pool_norm(
    const float* __restrict__ h32, const float* __restrict__ mask,
    float* __restrict__ out)
{
  __shared__ float red[8];
  int b = blockIdx.x, t = threadIdx.x;
  float a0 = 0.f, a1 = 0.f, a2 = 0.f;
  for (int s = 0; s < S_; ++s) {
    float m = mask[b*S_ + s];
    const float* hp = &h32[((size_t)b*S_ + s)*H_];
    a0 += hp[t]*m; a1 += hp[t+256]*m; a2 += hp[t+512]*m;
  }
  float msum = mask[b*S_ + t] + mask[b*S_ + 256 + t];
  float dummy = 0.f;
  block_sum2(msum, dummy, red);
  float inv = 1.f / fmaxf(msum, 1e-6f);
  float s0 = a0*inv, s1 = a1*inv, s2 = a2*inv;
  float nrm = s0*s0 + s1*s1 + s2*s2;
  dummy = 0.f;
  block_sum2(nrm, dummy, red);
  float rn = 1.f / fmaxf(sqrtf(nrm), 1e-12f);
  out[b*H_ + t]       = s0*rn;
  out[b*H_ + t + 256] = s1*rn;
  out[b*H_ + t + 512] = s2*rn;
}

// ---------------- host driver ----------------
extern "C" void kernel_launch(void* const* d_in, const int* in_sizes, int n_in,
                              void* d_out, int out_size, void* d_ws, size_t ws_size,
                              hipStream_t stream)
{
  const int*   ids  = (const int*)  d_in[0];
  const float* mask = (const float*)d_in[1];
  const float* we   = (const float*)d_in[2];
  const float* pe   = (const float*)d_in[3];
  const float* te   = (const float*)d_in[4];
  const float* les  = (const float*)d_in[5];
  const float* leb  = (const float*)d_in[6];
  const float* Wq   = (const float*)d_in[7];
  const float* bq   = (const float*)d_in[8];
  const float* Wk   = (const float*)d_in[9];
  const float* bk   = (const float*)d_in[10];
  const float* Wv   = (const float*)d_in[11];
  const float* bv   = (const float*)d_in[12];
  const float* Wo   = (const float*)d_in[13];
  const float* bo   = (const float*)d_in[14];
  const float* l1s  = (const float*)d_in[15];
  const float* l1b  = (const float*)d_in[16];
  const float* Wi   = (const float*)d_in[17];
  const float* bi   = (const float*)d_in[18];
  const float* Wf   = (const float*)d_in[19];
  const float* bfp  = (const float*)d_in[20];
  const float* l2s  = (const float*)d_in[21];
  const float* l2b  = (const float*)d_in[22];

  char* p = (char*)d_ws;
  auto alloc = [&](size_t bytes) { char* q = p; p += (bytes + 255) & ~(size_t)255; return q; };
  bf16*  wqkv = (bf16*) alloc((size_t)QKV_*H_*2);
  bf16*  wot  = (bf16*) alloc((size_t)H_*H_*2);
  bf16*  wit  = (bf16*) alloc((size_t)H_*FF_*2);
  bf16*  wft  = (bf16*) alloc((size_t)H_*FF_*2);
  float* qkbias=(float*)alloc((size_t)QKV_*4);
  bf16*  hb   = (bf16*) alloc((size_t)M_*H_*2);
  float* h32  = (float*)alloc((size_t)M_*H_*4);
  float* a32  = (float*)alloc((size_t)M_*H_*4);
  float* tmp  = (float*)alloc((size_t)M_*H_*4);
  bf16*  qkvb = (bf16*) alloc((size_t)M_*QKV_*2);
  bf16*  cxb  = (bf16*) alloc((size_t)M_*H_*2);
  bf16*  inb  = (bf16*) alloc((size_t)M_*FF_*2);

  embed_ln<<<M_, 256, 0, stream>>>(ids, we, pe, te, les, leb, h32, hb);

  for (int l = 0; l < L_; ++l) {
    size_t wsq = (size_t)l*H_*H_;
    transpose_w<<<dim3(H_/64,  H_/64 ), 256, 0, stream>>>(Wq + wsq, wqkv,            H_, H_);
    transpose_w<<<dim3(H_/64,  H_/64 ), 256, 0, stream>>>(Wk + wsq, wqkv + 768*768,  H_, H_);
    transpose_w<<<dim3(H_/64,  H_/64 ), 256, 0, stream>>>(Wv + wsq, wqkv + 2*768*768,H_, H_);
    transpose_w<<<dim3(H_/64,  H_/64 ), 256, 0, stream>>>(Wo + wsq, wot, H_, H_);
    transpose_w<<<dim3(H_/64,  FF_/64), 256, 0, stream>>>(Wi + (size_t)l*H_*FF_, wit, H_, FF_);
    transpose_w<<<dim3(FF_/64, H_/64 ), 256, 0, stream>>>(Wf + (size_t)l*FF_*H_, wft, FF_, H_);
    pack_qkv_bias<<<QKV_/256, 256, 0, stream>>>(bq + l*H_, bk + l*H_, bv + l*H_, qkbias);

    gemm128<<<128*(QKV_/128), 256, 0, stream>>>(hb,  wqkv, qkbias,      qkvb, QKV_, H_,  QKV_/128, 0);
    attn_kernel<<<B_*NH_*2, 512, 0, stream>>>(qkvb, mask, cxb);
    gemm128<<<128*(H_/128),  256, 0, stream>>>(cxb, wot, bo  + l*H_,  tmp,  H_,  H_,  H_/128,  1);
    ln_res<<<M_, 256, 0, stream>>>(tmp, h32, l1s + l*H_, l1b + l*H_, a32, hb);
    gemm128<<<128*(FF_/128), 256, 0, stream>>>(hb,  wit, bi  + l*FF_, inb,  FF_, H_,  FF_/128, 2);
    gemm128<<<128*(H_/128),  256, 0, stream>>>(inb, wft, bfp + l*H_,  tmp,  H_,  FF_, H_/128,  1);
    ln_res<<<M_, 256, 0, stream>>>(tmp, a32, l2s + l*H_, l2b + l*H_, h32, hb);
  }

  pool_norm<<<B_, 256, 0, stream>>>(h32, mask, (float*)d_out);
}